// Round 15
// baseline (607.536 us; speedup 1.0000x reference)
//
#include <hip/hip_runtime.h>
#include <hip/hip_bf16.h>
#include <hip/hip_cooperative_groups.h>

namespace cg = cooperative_groups;

#define HWC   2128      // H*W = 38*56
#define Hf    38
#define Wfv   56
#define CINv  1024
#define FPv   512       // FEAT_PLANES
#define RNUM  512
#define NCLSv 81
#define NOUT  85        // 81 cls + 4 loc
#define NBIN  49
#define KTOT  (NBIN * FPv)            // 25088
#define PARTN ((size_t)RNUM * NOUT)   // 43520

typedef short bf16x8 __attribute__((ext_vector_type(8)));
typedef float f32x4 __attribute__((ext_vector_type(4)));

static __device__ __forceinline__ unsigned short f2bf(float f) {
  __hip_bfloat16 h = __float2bfloat16(f);
  return *reinterpret_cast<unsigned short*>(&h);
}
static __device__ __forceinline__ float bflo(unsigned u) {
  return __uint_as_float((u & 0xffffu) << 16);
}
static __device__ __forceinline__ float bfhi(unsigned u) {
  return __uint_as_float(u & 0xffff0000u);
}

#define BSTRIDE1 136
#define B2STRIDE 136

// ===========================================================================
// MEGA KERNEL: all 5 phases in one cooperative launch, grid-stride per phase.
// Phase bodies are the verified R14 kernels verbatim (bitwise-same math).
// Shared mem: 26112-byte union (max over phases: gemm2's 96x136 bf16 tile).
// ===========================================================================
__global__ __launch_bounds__(256, 4) void mega_kernel(
    const float* __restrict__ rois, const float* __restrict__ feat,
    const float* __restrict__ w_new, const float* __restrict__ w_score,
    const float* __restrict__ b_score, const float* __restrict__ w_bbox,
    const float* __restrict__ b_bbox, const void* __restrict__ stridep,
    unsigned short* __restrict__ x_bf, unsigned short* __restrict__ P,
    unsigned short* __restrict__ Wt, unsigned short* __restrict__ featT,
    float* __restrict__ partial, unsigned short* __restrict__ wn_bf,
    float* __restrict__ bias_mean, float* __restrict__ out) {
  __shared__ __align__(16) char smem[26112];
  cg::grid_group gg = cg::this_grid();
  const int tid = threadIdx.x;
  const int nb = gridDim.x;
  const int lane = tid & 63, wid = tid >> 6;

  // ---------------- Phase 1: prep (7200 units) ----------------
  {
    float (*t)[33] = (float (*)[33])smem;
    for (int u = blockIdx.x; u < 7200; u += nb) {
      if (u >= 2912) {
        const int tb = u - 2912;
        const int bz = tb / 2144;
        const int rem = tb - bz * 2144;
        const int hw0 = (rem % 67) * 32;
        const int c0 = (rem / 67) * 32;
        const int tx = tid & 31, ty = tid >> 5;
        const float* fb = feat + (size_t)bz * CINv * HWC;
        const int hw = hw0 + tx;
#pragma unroll
        for (int i = 0; i < 4; ++i) {
          const int c = c0 + ty * 4 + i;
          t[ty * 4 + i][tx] = (hw < HWC) ? fb[(size_t)c * HWC + hw] : 0.f;
        }
        __syncthreads();
        unsigned short* ft = featT + (size_t)bz * HWC * CINv;
#pragma unroll
        for (int i = 0; i < 4; ++i) {
          const int hwo = hw0 + ty * 4 + i;
          if (hwo < HWC)
            ft[(size_t)hwo * CINv + c0 + tx] = f2bf(t[tx][ty * 4 + i]);
        }
      } else if (u >= 2400) {
        const int i = ((u - 2400) * 256 + tid) * 4;
        const float4 v = *(const float4*)(w_new + i);
        ushort4 o;
        o.x = f2bf(v.x); o.y = f2bf(v.y); o.z = f2bf(v.z); o.w = f2bf(v.w);
        *(ushort4*)(wn_bf + i) = o;
      } else {
        const int c = u % 96;
        const int by = u / 96;
        if (by == 0 && tid == 0) {
          float s = 0.f;
          if (c < NCLSv)
            for (int b = 0; b < NBIN; ++b) s += b_score[c * NBIN + b];
          else if (c < NOUT)
            for (int b = 0; b < NBIN; ++b) s += b_bbox[(c - NCLSv) * NBIN + b];
          bias_mean[c] = s * (1.0f / NBIN);
        }
        const int k0 = by * 1024 + tid * 4;
        if (k0 < KTOT) {
          const int bin = k0 >> 9, f = k0 & 511;
          float4 v = make_float4(0.f, 0.f, 0.f, 0.f);
          if (c < NCLSv)
            v = *(const float4*)(w_score + ((size_t)(c * NBIN + bin)) * FPv + f);
          else if (c < NOUT)
            v = *(const float4*)(w_bbox + ((size_t)((c - NCLSv) * NBIN + bin)) * FPv + f);
          ushort4 o;
          o.x = f2bf(v.x); o.y = f2bf(v.y); o.z = f2bf(v.z); o.w = f2bf(v.w);
          *(ushort4*)(Wt + ((size_t)bin * 96 + c) * FPv + f) = o;
        }
      }
      __syncthreads();  // smem reuse guard across units
    }
  }
  gg.sync();

  // ---------------- Phase 2: gemm1 v3 (1088 units = 34 x 16 x 2) ----------
  {
    unsigned short* Bs = (unsigned short*)smem;  // 32 x 136
    for (int u = blockIdx.x; u < 1088; u += nb) {
      const int bx = u % 34;
      const int r2 = u / 34;
      const int by = r2 & 15;
      const int bz = r2 >> 4;
      const int f0 = by * 32;
      const int hwbase = bx * 64 + wid * 16;
      const int arow = min(hwbase + (lane & 15), HWC - 1);
      const int fr_f = lane & 15;
      const int fr_k = (lane >> 4) << 3;
      const unsigned short* Ap =
          featT + ((size_t)bz * HWC + arow) * CINv + fr_k;
      const int sr = tid >> 3;
      const int sc = (tid & 7) * 16;
      const unsigned short* Bg = wn_bf + (size_t)(f0 + sr) * CINv + sc;

      uint4 breg[2];
      bf16x8 aCur[4], aNxt[4];
      breg[0] = *(const uint4*)(Bg);
      breg[1] = *(const uint4*)(Bg + 8);
#pragma unroll
      for (int s = 0; s < 4; ++s) aCur[s] = *(const bf16x8*)(Ap + s * 32);

      f32x4 acc[2] = {};
      for (int kc = 0; kc < CINv; kc += 128) {
        __syncthreads();
        *(uint4*)&Bs[sr * BSTRIDE1 + sc] = breg[0];
        *(uint4*)&Bs[sr * BSTRIDE1 + sc + 8] = breg[1];
        const int kn = kc + 128;
        if (kn < CINv) {
          breg[0] = *(const uint4*)(Bg + kn);
          breg[1] = *(const uint4*)(Bg + kn + 8);
#pragma unroll
          for (int s = 0; s < 4; ++s)
            aNxt[s] = *(const bf16x8*)(Ap + kn + s * 32);
        }
        __syncthreads();
#pragma unroll
        for (int s = 0; s < 4; ++s) {
#pragma unroll
          for (int n = 0; n < 2; ++n) {
            const bf16x8 bv = *(const bf16x8*)
                &Bs[(fr_f + n * 16) * BSTRIDE1 + s * 32 + fr_k];
            acc[n] = __builtin_amdgcn_mfma_f32_16x16x32_bf16(aCur[s], bv,
                                                             acc[n], 0, 0, 0);
          }
        }
#pragma unroll
        for (int s = 0; s < 4; ++s) aCur[s] = aNxt[s];
      }
      const int c_lo = lane & 15;
      const int rbase = hwbase + ((lane >> 4) << 2);
#pragma unroll
      for (int n = 0; n < 2; ++n) {
#pragma unroll
        for (int reg = 0; reg < 4; ++reg) {
          const int hwo = rbase + reg;
          if (hwo < HWC)
            x_bf[((size_t)bz * HWC + hwo) * FPv + f0 + n * 16 + c_lo] =
                f2bf(acc[n][reg]);
        }
      }
    }
  }
  gg.sync();

  // ---------------- Phase 3: pool (3584 units = 512 r x 7 ph) -------------
  {
    struct PoolS {
      int ys0[2], ys1[2];
      float wys[2];
      int xs0[14], xs1[14];
      float wxs[14];
    };
    PoolS* ps = (PoolS*)smem;
    unsigned int* P_u = (unsigned int*)P;
    for (int u = blockIdx.x; u < 3584; u += nb) {
      const int r = u & 511;
      const int ph = u >> 9;
      const float* ro = rois + (size_t)r * 5;

      float stride_f;
      {
        const int iv = ((const int*)stridep)[0];
        if (iv >= 1 && iv <= 4096) stride_f = (float)iv;
        else stride_f = ((const float*)stridep)[0];
      }
      const float inv = 1.0f / stride_f;

      if (tid < 2) {
        const float y1v = ro[2] * inv, y2v = ro[4] * inv;
        const float bhf = fmaxf(y2v - y1v, 0.1f) * (1.0f / 7.0f);
        const int sy = tid;
        float yy = y1v + ((float)ph + ((float)sy + 0.5f) * 0.5f) * bhf;
        yy = fminf(fmaxf(yy, 0.f), (float)(Hf - 1));
        const float y0f = floorf(yy);
        ps->ys0[tid] = (int)y0f;
        ps->ys1[tid] = min((int)y0f + 1, Hf - 1);
        ps->wys[tid] = yy - y0f;
      } else if (tid >= 64 && tid < 78) {
        const int s = tid - 64;
        const float x1v = ro[1] * inv, x2v = ro[3] * inv;
        const float bwf = fmaxf(x2v - x1v, 0.1f) * (1.0f / 7.0f);
        const int pw = s >> 1, sx = s & 1;
        float xx = x1v + ((float)pw + ((float)sx + 0.5f) * 0.5f) * bwf;
        xx = fminf(fmaxf(xx, 0.f), (float)(Wfv - 1));
        const float x0f = floorf(xx);
        ps->xs0[s] = (int)x0f;
        ps->xs1[s] = min((int)x0f + 1, Wfv - 1);
        ps->wxs[s] = xx - x0f;
      }
      __syncthreads();

      const int b = (int)ro[0];
      const unsigned short* xb = x_bf + (size_t)b * HWC * FPv;
      const int f2 = tid * 2;

      float acc[7][2] = {};
#pragma unroll
      for (int sy = 0; sy < 2; ++sy) {
        const int ry0 = ps->ys0[sy] * Wfv;
        const int ry1 = ps->ys1[sy] * Wfv;
        const float wy = ps->wys[sy];
        const float cy = 1.f - wy;
#pragma unroll
        for (int pwsx = 0; pwsx < 14; ++pwsx) {
          const int xi0 = ps->xs0[pwsx], xi1 = ps->xs1[pwsx];
          const float wx = ps->wxs[pwsx];
          const float cx = 1.f - wx;
          const unsigned u00 = *(const unsigned*)(xb + (size_t)(ry0 + xi0) * FPv + f2);
          const unsigned u01 = *(const unsigned*)(xb + (size_t)(ry0 + xi1) * FPv + f2);
          const unsigned u10 = *(const unsigned*)(xb + (size_t)(ry1 + xi0) * FPv + f2);
          const unsigned u11 = *(const unsigned*)(xb + (size_t)(ry1 + xi1) * FPv + f2);
          const float w00 = cy * cx, w01 = cy * wx, w10 = wy * cx, w11 = wy * wx;
          const int pw = pwsx >> 1;
          acc[pw][0] += w00 * bflo(u00) + w01 * bflo(u01) + w10 * bflo(u10) + w11 * bflo(u11);
          acc[pw][1] += w00 * bfhi(u00) + w01 * bfhi(u01) + w10 * bfhi(u10) + w11 * bfhi(u11);
        }
      }
#pragma unroll
      for (int pw = 0; pw < 7; ++pw) {
        const unsigned lo = f2bf(acc[pw][0] * 0.25f);
        const unsigned hi = f2bf(acc[pw][1] * 0.25f);
        P_u[((size_t)(ph * 7 + pw) * RNUM + r) * (FPv / 2) + tid] =
            lo | (hi << 16);
      }
      __syncthreads();  // smem reuse guard
    }
  }
  gg.sync();

  // ---------------- Phase 4: gemm2 (392 units = 8 rt x 49 bin) ------------
  {
    unsigned short* Bs = (unsigned short*)smem;  // 96 x 136
    for (int u = blockIdx.x; u < 392; u += nb) {
      const int rt = u & 7;
      const int bin = u >> 3;
      const int arow = rt * 64 + wid * 16 + (lane & 15);
      const int fr_f = lane & 15;
      const int fr_k = (lane >> 4) << 3;
      const unsigned short* Ap = P + ((size_t)bin * RNUM + arow) * FPv + fr_k;
      int srow[3], scol[3];
#pragma unroll
      for (int g = 0; g < 3; ++g) {
        const int idx = tid * 48 + g * 16;
        srow[g] = idx >> 7;
        scol[g] = idx & 127;
      }
      const unsigned short* WtB = Wt + (size_t)bin * 96 * FPv;

      uint4 breg[6];
      bf16x8 aCur[4], aNxt[4];
#pragma unroll
      for (int g = 0; g < 3; ++g) {
        const unsigned short* src = WtB + (size_t)srow[g] * FPv + scol[g];
        breg[g * 2] = *(const uint4*)src;
        breg[g * 2 + 1] = *(const uint4*)(src + 8);
      }
#pragma unroll
      for (int s = 0; s < 4; ++s) aCur[s] = *(const bf16x8*)(Ap + s * 32);

      f32x4 acc[6] = {};
      for (int kc = 0; kc < FPv; kc += 128) {
        __syncthreads();
#pragma unroll
        for (int g = 0; g < 3; ++g) {
          unsigned short* dst = &Bs[srow[g] * B2STRIDE + scol[g]];
          *(uint4*)dst = breg[g * 2];
          *(uint4*)(dst + 8) = breg[g * 2 + 1];
        }
        const int kn = kc + 128;
        if (kn < FPv) {
#pragma unroll
          for (int g = 0; g < 3; ++g) {
            const unsigned short* src =
                WtB + (size_t)srow[g] * FPv + kn + scol[g];
            breg[g * 2] = *(const uint4*)src;
            breg[g * 2 + 1] = *(const uint4*)(src + 8);
          }
#pragma unroll
          for (int s = 0; s < 4; ++s)
            aNxt[s] = *(const bf16x8*)(Ap + kn + s * 32);
        }
        __syncthreads();
#pragma unroll
        for (int s = 0; s < 4; ++s) {
#pragma unroll
          for (int n = 0; n < 6; ++n) {
            const bf16x8 bv = *(const bf16x8*)
                &Bs[(fr_f + n * 16) * B2STRIDE + s * 32 + fr_k];
            acc[n] = __builtin_amdgcn_mfma_f32_16x16x32_bf16(aCur[s], bv,
                                                             acc[n], 0, 0, 0);
          }
        }
#pragma unroll
        for (int s = 0; s < 4; ++s) aCur[s] = aNxt[s];
      }
      const int c_lo = lane & 15;
      const int rr = rt * 64 + wid * 16 + ((lane >> 4) << 2);
      float* pb = partial + (size_t)bin * PARTN;
#pragma unroll
      for (int n = 0; n < 6; ++n) {
        const int c = n * 16 + c_lo;
        if (c < NOUT) {
#pragma unroll
          for (int reg = 0; reg < 4; ++reg)
            pb[(size_t)(rr + reg) * NOUT + c] = acc[n][reg];
        }
      }
    }
  }
  gg.sync();

  // ---------------- Phase 5: reduce (170 units) ----------------------------
  for (int u = blockIdx.x; u < 170; u += nb) {
    const int g = u * 256 + tid;
    const int r = g / NOUT;
    const int cc = g - r * NOUT;
    float s = 0.f;
    for (int b = 0; b < NBIN; ++b) s += partial[(size_t)b * PARTN + g];
    s = s * (1.0f / NBIN) + bias_mean[cc];
    if (cc < NCLSv)
      out[(size_t)r * NCLSv + cc] = s;
    else
      out[(size_t)RNUM * NCLSv + (size_t)r * 4 + (cc - NCLSv)] = s;
  }
}

// ===========================================================================
// Fallback path: the verified R14 5-kernel pipeline (verbatim).
// ===========================================================================
__global__ __launch_bounds__(256) void prep_kernel(
    const float* __restrict__ w_score, const float* __restrict__ b_score,
    const float* __restrict__ w_bbox, const float* __restrict__ b_bbox,
    const float* __restrict__ w_new, const float* __restrict__ feat,
    unsigned short* __restrict__ Wt, float* __restrict__ bias_mean,
    unsigned short* __restrict__ wn_bf, unsigned short* __restrict__ featT) {
  __shared__ float t[32][33];
  const int bid = blockIdx.x;
  const int tid = threadIdx.x;
  if (bid >= 2912) {
    const int tb = bid - 2912;
    const int bz = tb / 2144;
    const int rem = tb - bz * 2144;
    const int hw0 = (rem % 67) * 32;
    const int c0 = (rem / 67) * 32;
    const int tx = tid & 31, ty = tid >> 5;
    const float* fb = feat + (size_t)bz * CINv * HWC;
    const int hw = hw0 + tx;
#pragma unroll
    for (int i = 0; i < 4; ++i) {
      const int c = c0 + ty * 4 + i;
      t[ty * 4 + i][tx] = (hw < HWC) ? fb[(size_t)c * HWC + hw] : 0.f;
    }
    __syncthreads();
    unsigned short* ft = featT + (size_t)bz * HWC * CINv;
#pragma unroll
    for (int i = 0; i < 4; ++i) {
      const int hwo = hw0 + ty * 4 + i;
      if (hwo < HWC) ft[(size_t)hwo * CINv + c0 + tx] = f2bf(t[tx][ty * 4 + i]);
    }
    return;
  }
  if (bid >= 2400) {
    const int i = ((bid - 2400) * 256 + tid) * 4;
    const float4 v = *(const float4*)(w_new + i);
    ushort4 o;
    o.x = f2bf(v.x); o.y = f2bf(v.y); o.z = f2bf(v.z); o.w = f2bf(v.w);
    *(ushort4*)(wn_bf + i) = o;
    return;
  }
  const int c = bid % 96;
  const int by = bid / 96;
  if (by == 0 && tid == 0) {
    float s = 0.f;
    if (c < NCLSv)
      for (int b = 0; b < NBIN; ++b) s += b_score[c * NBIN + b];
    else if (c < NOUT)
      for (int b = 0; b < NBIN; ++b) s += b_bbox[(c - NCLSv) * NBIN + b];
    bias_mean[c] = s * (1.0f / NBIN);
  }
  const int k0 = by * 1024 + tid * 4;
  if (k0 >= KTOT) return;
  const int bin = k0 >> 9, f = k0 & 511;
  float4 v = make_float4(0.f, 0.f, 0.f, 0.f);
  if (c < NCLSv)
    v = *(const float4*)(w_score + ((size_t)(c * NBIN + bin)) * FPv + f);
  else if (c < NOUT)
    v = *(const float4*)(w_bbox + ((size_t)((c - NCLSv) * NBIN + bin)) * FPv + f);
  ushort4 o;
  o.x = f2bf(v.x); o.y = f2bf(v.y); o.z = f2bf(v.z); o.w = f2bf(v.w);
  *(ushort4*)(Wt + ((size_t)bin * 96 + c) * FPv + f) = o;
}

__global__ __launch_bounds__(256) void gemm1_mfma_kernel(
    const unsigned short* __restrict__ featT,
    const unsigned short* __restrict__ wn_bf,
    unsigned short* __restrict__ x_bf) {
  __shared__ unsigned short Bs[32 * BSTRIDE1];
  const int tid = threadIdx.x;
  const int lane = tid & 63, wid = tid >> 6;
  const int f0 = blockIdx.y * 32;
  const int b = blockIdx.z;
  const int hwbase = blockIdx.x * 64 + wid * 16;
  const int arow = min(hwbase + (lane & 15), HWC - 1);
  const int fr_f = lane & 15;
  const int fr_k = (lane >> 4) << 3;
  const unsigned short* Ap = featT + ((size_t)b * HWC + arow) * CINv + fr_k;
  const int sr = tid >> 3;
  const int sc = (tid & 7) * 16;
  const unsigned short* Bg = wn_bf + (size_t)(f0 + sr) * CINv + sc;

  uint4 breg[2];
  bf16x8 aCur[4], aNxt[4];
  breg[0] = *(const uint4*)(Bg);
  breg[1] = *(const uint4*)(Bg + 8);
#pragma unroll
  for (int s = 0; s < 4; ++s) aCur[s] = *(const bf16x8*)(Ap + s * 32);

  f32x4 acc[2] = {};
  for (int kc = 0; kc < CINv; kc += 128) {
    __syncthreads();
    *(uint4*)&Bs[sr * BSTRIDE1 + sc] = breg[0];
    *(uint4*)&Bs[sr * BSTRIDE1 + sc + 8] = breg[1];
    const int kn = kc + 128;
    if (kn < CINv) {
      breg[0] = *(const uint4*)(Bg + kn);
      breg[1] = *(const uint4*)(Bg + kn + 8);
#pragma unroll
      for (int s = 0; s < 4; ++s) aNxt[s] = *(const bf16x8*)(Ap + kn + s * 32);
    }
    __syncthreads();
#pragma unroll
    for (int s = 0; s < 4; ++s) {
#pragma unroll
      for (int n = 0; n < 2; ++n) {
        const bf16x8 bv =
            *(const bf16x8*)&Bs[(fr_f + n * 16) * BSTRIDE1 + s * 32 + fr_k];
        acc[n] =
            __builtin_amdgcn_mfma_f32_16x16x32_bf16(aCur[s], bv, acc[n], 0, 0, 0);
      }
    }
#pragma unroll
    for (int s = 0; s < 4; ++s) aCur[s] = aNxt[s];
  }
  const int c_lo = lane & 15;
  const int rbase = hwbase + ((lane >> 4) << 2);
#pragma unroll
  for (int n = 0; n < 2; ++n) {
#pragma unroll
    for (int reg = 0; reg < 4; ++reg) {
      const int hwo = rbase + reg;
      if (hwo < HWC)
        x_bf[((size_t)b * HWC + hwo) * FPv + f0 + n * 16 + c_lo] =
            f2bf(acc[n][reg]);
    }
  }
}

__global__ __launch_bounds__(256) void pool_kernel(
    const unsigned short* __restrict__ x_bf, const float* __restrict__ rois,
    const void* __restrict__ stride_ptr, unsigned int* __restrict__ P_u) {
  __shared__ int ys0[2], ys1[2];
  __shared__ float wys[2];
  __shared__ int xs0[14], xs1[14];
  __shared__ float wxs[14];
  const int tid = threadIdx.x;
  const int r = blockIdx.x;
  const int ph = blockIdx.y;
  const float* ro = rois + (size_t)r * 5;

  float stride_f;
  {
    const int iv = ((const int*)stride_ptr)[0];
    if (iv >= 1 && iv <= 4096) stride_f = (float)iv;
    else stride_f = ((const float*)stride_ptr)[0];
  }
  const float inv = 1.0f / stride_f;

  if (tid < 2) {
    const float y1v = ro[2] * inv, y2v = ro[4] * inv;
    const float bhf = fmaxf(y2v - y1v, 0.1f) * (1.0f / 7.0f);
    const int sy = tid;
    float yy = y1v + ((float)ph + ((float)sy + 0.5f) * 0.5f) * bhf;
    yy = fminf(fmaxf(yy, 0.f), (float)(Hf - 1));
    const float y0f = floorf(yy);
    ys0[tid] = (int)y0f;
    ys1[tid] = min((int)y0f + 1, Hf - 1);
    wys[tid] = yy - y0f;
  } else if (tid >= 64 && tid < 78) {
    const int s = tid - 64;
    const float x1v = ro[1] * inv, x2v = ro[3] * inv;
    const float bwf = fmaxf(x2v - x1v, 0.1f) * (1.0f / 7.0f);
    const int pw = s >> 1, sx = s & 1;
    float xx = x1v + ((float)pw + ((float)sx + 0.5f) * 0.5f) * bwf;
    xx = fminf(fmaxf(xx, 0.f), (float)(Wfv - 1));
    const float x0f = floorf(xx);
    xs0[s] = (int)x0f;
    xs1[s] = min((int)x0f + 1, Wfv - 1);
    wxs[s] = xx - x0f;
  }
  __syncthreads();

  const int b = (int)ro[0];
  const unsigned short* xb = x_bf + (size_t)b * HWC * FPv;
  const int f2 = tid * 2;

  float acc[7][2] = {};
#pragma unroll
  for (int sy = 0; sy < 2; ++sy) {
    const int ry0 = ys0[sy] * Wfv;
    const int ry1 = ys1[sy] * Wfv;
    const float wy = wys[sy];
    const float cy = 1.f - wy;
#pragma unroll
    for (int pwsx = 0; pwsx < 14; ++pwsx) {
      const int xi0 = xs0[pwsx], xi1 = xs1[pwsx];
      const float wx = wxs[pwsx];
      const float cx = 1.f - wx;
      const unsigned u00 = *(const unsigned*)(xb + (size_t)(ry0 + xi0) * FPv + f2);
      const unsigned u01 = *(const unsigned*)(xb + (size_t)(ry0 + xi1) * FPv + f2);
      const unsigned u10 = *(const unsigned*)(xb + (size_t)(ry1 + xi0) * FPv + f2);
      const unsigned u11 = *(const unsigned*)(xb + (size_t)(ry1 + xi1) * FPv + f2);
      const float w00 = cy * cx, w01 = cy * wx, w10 = wy * cx, w11 = wy * wx;
      const int pw = pwsx >> 1;
      acc[pw][0] += w00 * bflo(u00) + w01 * bflo(u01) + w10 * bflo(u10) + w11 * bflo(u11);
      acc[pw][1] += w00 * bfhi(u00) + w01 * bfhi(u01) + w10 * bfhi(u10) + w11 * bfhi(u11);
    }
  }
#pragma unroll
  for (int pw = 0; pw < 7; ++pw) {
    const unsigned lo = f2bf(acc[pw][0] * 0.25f);
    const unsigned hi = f2bf(acc[pw][1] * 0.25f);
    P_u[((size_t)(ph * 7 + pw) * RNUM + r) * (FPv / 2) + tid] = lo | (hi << 16);
  }
}

__global__ __launch_bounds__(256) void gemm2_kernel(
    const unsigned short* __restrict__ P, const unsigned short* __restrict__ Wt,
    float* __restrict__ partial) {
  __shared__ unsigned short Bs[96 * B2STRIDE];
  const int tid = threadIdx.x;
  const int lane = tid & 63, wid = tid >> 6;
  const int rt = blockIdx.x;
  const int bin = blockIdx.y;
  const int arow = rt * 64 + wid * 16 + (lane & 15);
  const int fr_f = lane & 15;
  const int fr_k = (lane >> 4) << 3;
  const unsigned short* Ap = P + ((size_t)bin * RNUM + arow) * FPv + fr_k;
  int srow[3], scol[3];
#pragma unroll
  for (int g = 0; g < 3; ++g) {
    const int idx = tid * 48 + g * 16;
    srow[g] = idx >> 7;
    scol[g] = idx & 127;
  }
  const unsigned short* WtB = Wt + (size_t)bin * 96 * FPv;

  uint4 breg[6];
  bf16x8 aCur[4], aNxt[4];
#pragma unroll
  for (int g = 0; g < 3; ++g) {
    const unsigned short* src = WtB + (size_t)srow[g] * FPv + scol[g];
    breg[g * 2] = *(const uint4*)src;
    breg[g * 2 + 1] = *(const uint4*)(src + 8);
  }
#pragma unroll
  for (int s = 0; s < 4; ++s) aCur[s] = *(const bf16x8*)(Ap + s * 32);

  f32x4 acc[6] = {};
  for (int kc = 0; kc < FPv; kc += 128) {
    __syncthreads();
#pragma unroll
    for (int g = 0; g < 3; ++g) {
      unsigned short* dst = &Bs[srow[g] * B2STRIDE + scol[g]];
      *(uint4*)dst = breg[g * 2];
      *(uint4*)(dst + 8) = breg[g * 2 + 1];
    }
    const int kn = kc + 128;
    if (kn < FPv) {
#pragma unroll
      for (int g = 0; g < 3; ++g) {
        const unsigned short* src = WtB + (size_t)srow[g] * FPv + kn + scol[g];
        breg[g * 2] = *(const uint4*)src;
        breg[g * 2 + 1] = *(const uint4*)(src + 8);
      }
#pragma unroll
      for (int s = 0; s < 4; ++s) aNxt[s] = *(const bf16x8*)(Ap + kn + s * 32);
    }
    __syncthreads();
#pragma unroll
    for (int s = 0; s < 4; ++s) {
#pragma unroll
      for (int n = 0; n < 6; ++n) {
        const bf16x8 bv =
            *(const bf16x8*)&Bs[(fr_f + n * 16) * B2STRIDE + s * 32 + fr_k];
        acc[n] =
            __builtin_amdgcn_mfma_f32_16x16x32_bf16(aCur[s], bv, acc[n], 0, 0, 0);
      }
    }
#pragma unroll
    for (int s = 0; s < 4; ++s) aCur[s] = aNxt[s];
  }
  const int c_lo = lane & 15;
  const int rr = rt * 64 + wid * 16 + ((lane >> 4) << 2);
  float* pb = partial + (size_t)bin * PARTN;
#pragma unroll
  for (int n = 0; n < 6; ++n) {
    const int c = n * 16 + c_lo;
    if (c < NOUT) {
#pragma unroll
      for (int reg = 0; reg < 4; ++reg)
        pb[(size_t)(rr + reg) * NOUT + c] = acc[n][reg];
    }
  }
}

__global__ __launch_bounds__(256) void reduce_kernel(
    const float* __restrict__ partial, const float* __restrict__ bias_mean,
    float* __restrict__ out) {
  const int g = blockIdx.x * 256 + threadIdx.x;
  const int r = g / NOUT;
  const int cc = g - r * NOUT;
  float s = 0.f;
  for (int b = 0; b < NBIN; ++b) s += partial[(size_t)b * PARTN + g];
  s = s * (1.0f / NBIN) + bias_mean[cc];
  if (cc < NCLSv)
    out[(size_t)r * NCLSv + cc] = s;
  else
    out[(size_t)RNUM * NCLSv + (size_t)r * 4 + (cc - NCLSv)] = s;
}

// ---------------------------------------------------------------------------
extern "C" void kernel_launch(void* const* d_in, const int* in_sizes, int n_in,
                              void* d_out, int out_size, void* d_ws,
                              size_t ws_size, hipStream_t stream) {
  const float* rois    = (const float*)d_in[0];
  const float* feat    = (const float*)d_in[1];
  const float* w_new   = (const float*)d_in[2];
  const float* w_score = (const float*)d_in[3];
  const float* b_score = (const float*)d_in[4];
  const float* w_bbox  = (const float*)d_in[5];
  const float* b_bbox  = (const float*)d_in[6];
  const void*  stridep = d_in[7];
  float* out = (float*)d_out;

  // ws layout (256B-aligned). featT (dead after gemm1) aliases partial.
  char* w = (char*)d_ws;
  unsigned short* x_bf = (unsigned short*)w;
  w += ((size_t)2 * HWC * FPv * 2 + 255) & ~(size_t)255;
  unsigned short* P = (unsigned short*)w;
  w += ((size_t)RNUM * KTOT * 2 + 255) & ~(size_t)255;
  unsigned short* Wt = (unsigned short*)w;
  w += ((size_t)96 * KTOT * 2 + 255) & ~(size_t)255;
  char* shared_blk = w;
  unsigned short* featT = (unsigned short*)shared_blk;
  float* partial = (float*)shared_blk;
  w += ((size_t)2 * HWC * CINv * 2 + 255) & ~(size_t)255;
  unsigned short* wn_bf = (unsigned short*)w;
  w += ((size_t)FPv * CINv * 2 + 255) & ~(size_t)255;
  float* bias_mean = (float*)w;

  void* args[] = {(void*)&rois,   (void*)&feat,    (void*)&w_new,
                  (void*)&w_score,(void*)&b_score, (void*)&w_bbox,
                  (void*)&b_bbox, (void*)&stridep, (void*)&x_bf,
                  (void*)&P,      (void*)&Wt,      (void*)&featT,
                  (void*)&partial,(void*)&wn_bf,   (void*)&bias_mean,
                  (void*)&out};
  hipError_t e = hipLaunchCooperativeKernel((const void*)mega_kernel,
                                            dim3(960), dim3(256), args, 0,
                                            stream);
  if (e != hipSuccess) {
    // Fallback: verified R14 5-kernel pipeline (identical outputs).
    prep_kernel<<<7200, 256, 0, stream>>>(w_score, b_score, w_bbox, b_bbox,
                                          w_new, feat, Wt, bias_mean, wn_bf,
                                          featT);
    {
      dim3 grid(34, FPv / 32, 2);
      gemm1_mfma_kernel<<<grid, 256, 0, stream>>>(featT, wn_bf, x_bf);
    }
    {
      dim3 grid(RNUM, 7);
      pool_kernel<<<grid, 256, 0, stream>>>(x_bf, rois, stridep,
                                            (unsigned int*)P);
    }
    {
      dim3 grid(RNUM / 64, NBIN);
      gemm2_kernel<<<grid, 256, 0, stream>>>(P, Wt, partial);
    }
    reduce_kernel<<<(RNUM * NOUT) / 256, 256, 0, stream>>>(partial, bias_mean,
                                                           out);
  }
}

// Round 16
// 115.311 us; speedup vs baseline: 5.2687x; 5.2687x over previous
//
#include <hip/hip_runtime.h>
#include <hip/hip_bf16.h>

#define HWC   2128      // H*W = 38*56
#define Hf    38
#define Wfv   56
#define CINv  1024
#define FPv   512       // FEAT_PLANES
#define RNUM  512
#define NCLSv 81
#define NOUT  85        // 81 cls + 4 loc
#define NBIN  49
#define KTOT  (NBIN * FPv)            // 25088
#define PARTN ((size_t)RNUM * NOUT)   // 43520

typedef short bf16x8 __attribute__((ext_vector_type(8)));
typedef float f32x4 __attribute__((ext_vector_type(4)));

static __device__ __forceinline__ unsigned short f2bf(float f) {
  __hip_bfloat16 h = __float2bfloat16(f);
  return *reinterpret_cast<unsigned short*>(&h);
}
static __device__ __forceinline__ float bflo(unsigned u) {
  return __uint_as_float((u & 0xffffu) << 16);
}
static __device__ __forceinline__ float bfhi(unsigned u) {
  return __uint_as_float(u & 0xffff0000u);
}

#define B2STRIDE 136

// ---------------------------------------------------------------------------
// Kernel 0 (prep-lite): 4800 blocks.
//   [0,512):    w_new fp32 -> bf16
//   [512,4800): feat -> featT transpose/convert (R14 XCD-swizzled order)
// (Wt prepack moved into the pool launch — off gemm1's critical path.)
// ---------------------------------------------------------------------------
__global__ __launch_bounds__(256) void prep_kernel(
    const float* __restrict__ w_new, const float* __restrict__ feat,
    unsigned short* __restrict__ wn_bf, unsigned short* __restrict__ featT) {
  __shared__ float t[32][33];
  const int bid = blockIdx.x;
  const int tid = threadIdx.x;
  if (bid < 512) {
    const int i = (bid * 256 + tid) * 4;  // < 512*1024
    const float4 v = *(const float4*)(w_new + i);
    ushort4 o;
    o.x = f2bf(v.x); o.y = f2bf(v.y); o.z = f2bf(v.z); o.w = f2bf(v.w);
    *(ushort4*)(wn_bf + i) = o;
    return;
  }
  const int t_ = bid - 512;                     // 0..4287
  const int wgid = (t_ & 7) * 536 + (t_ >> 3);  // bijective, 4288 = 8*536
  const int h32 = wgid >> 6;                    // 0..66
  const int rem = wgid & 63;
  const int c32 = rem >> 1;                     // 0..31
  const int bz = rem & 1;
  const int hw0 = h32 * 32;
  const int c0 = c32 * 32;
  const int tx = tid & 31, ty = tid >> 5;  // 32 x 8
  const float* fb = feat + (size_t)bz * CINv * HWC;
  const int hw = hw0 + tx;
#pragma unroll
  for (int i = 0; i < 4; ++i) {
    const int c = c0 + ty * 4 + i;
    t[ty * 4 + i][tx] = (hw < HWC) ? fb[(size_t)c * HWC + hw] : 0.f;
  }
  __syncthreads();
  unsigned short* ft = featT + (size_t)bz * HWC * CINv;
#pragma unroll
  for (int i = 0; i < 4; ++i) {
    const int hwo = hw0 + ty * 4 + i;
    if (hwo < HWC) ft[(size_t)hwo * CINv + c0 + tx] = f2bf(t[tx][ty * 4 + i]);
  }
}

// ---------------------------------------------------------------------------
// Kernel 1: MFMA GEMM v6 — barrier-free, LDS-free, explicit 4-deep register
// pipeline on all 3 operands (v5's verified indexing + the prefetch the
// compiler refused to create: 12 loads in flight, counted vmcnt).
// Grid 1064 = 8 XCD x 133; one wave per 16hw x 32f; K-order identical to
// v2..v5 -> bitwise-same x_bf.
// ---------------------------------------------------------------------------
__global__ __launch_bounds__(256) void gemm1_mfma_kernel(
    const unsigned short* __restrict__ featT,
    const unsigned short* __restrict__ wn_bf,
    unsigned short* __restrict__ x_bf) {
  const int tid = threadIdx.x;
  const int lane = tid & 63, wid = tid >> 6;  // 4 waves
  const int orig = blockIdx.x;                // 1064 = 8 * 133
  const int wgid = (orig & 7) * 133 + (orig >> 3);
  const int hwg = wgid >> 2;                  // 0..265 (hw slowest)
  const int fb = wgid & 3;                    // 0..3
  const int f0 = fb * 128 + wid * 32;
  const int b = (hwg >= 133) ? 1 : 0;         // 2128 = 133*16 exactly
  const int hwbase = (hwg - b * 133) * 16;
  const int arow = hwbase + (lane & 15);
  const int koff = (lane >> 4) << 3;
  const unsigned short* Ap = featT + ((size_t)b * HWC + arow) * CINv + koff;
  const unsigned short* Bp0 = wn_bf + (size_t)(f0 + (lane & 15)) * CINv + koff;
  const unsigned short* Bp1 = Bp0 + (size_t)16 * CINv;

  bf16x8 av[4], b0v[4], b1v[4];
#pragma unroll
  for (int g = 0; g < 4; ++g) {
    av[g]  = *(const bf16x8*)(Ap  + g * 32);
    b0v[g] = *(const bf16x8*)(Bp0 + g * 32);
    b1v[g] = *(const bf16x8*)(Bp1 + g * 32);
  }
  f32x4 acc0 = {}, acc1 = {};
#pragma unroll
  for (int ks = 0; ks < 32; ++ks) {
    const int slot = ks & 3;  // compile-time after full unroll
    const bf16x8 a = av[slot];
    const bf16x8 b0 = b0v[slot];
    const bf16x8 b1 = b1v[slot];
    if (ks + 4 < 32) {
      av[slot]  = *(const bf16x8*)(Ap  + (ks + 4) * 32);
      b0v[slot] = *(const bf16x8*)(Bp0 + (ks + 4) * 32);
      b1v[slot] = *(const bf16x8*)(Bp1 + (ks + 4) * 32);
    }
    acc0 = __builtin_amdgcn_mfma_f32_16x16x32_bf16(a, b0, acc0, 0, 0, 0);
    acc1 = __builtin_amdgcn_mfma_f32_16x16x32_bf16(a, b1, acc1, 0, 0, 0);
  }
  // D: col = lane&15 (f), row = (lane>>4)*4 + reg (hw); all rows valid.
  const int c_lo = lane & 15;
  const int rbase = hwbase + ((lane >> 4) << 2);
#pragma unroll
  for (int reg = 0; reg < 4; ++reg) {
    const size_t rowoff = ((size_t)b * HWC + rbase + reg) * FPv;
    x_bf[rowoff + f0 + c_lo] = f2bf(acc0[reg]);
    x_bf[rowoff + f0 + 16 + c_lo] = f2bf(acc1[reg]);
  }
}

// ---------------------------------------------------------------------------
// Kernel 2 (pool + Wt-prepack, block-range split; bodies verbatim R14):
//   [0,3584):    PSRoI pooling -> P[bin][r][f]  (r = u&511, ph = u>>9)
//   [3584,5984): Wt[bin][96][512] prepack + bias_mean[96]
// ---------------------------------------------------------------------------
__global__ __launch_bounds__(256) void pool_prep_kernel(
    const unsigned short* __restrict__ x_bf, const float* __restrict__ rois,
    const void* __restrict__ stride_ptr, unsigned int* __restrict__ P_u,
    const float* __restrict__ w_score, const float* __restrict__ b_score,
    const float* __restrict__ w_bbox, const float* __restrict__ b_bbox,
    unsigned short* __restrict__ Wt, float* __restrict__ bias_mean) {
  __shared__ int ys0[2], ys1[2];
  __shared__ float wys[2];
  __shared__ int xs0[14], xs1[14];
  __shared__ float wxs[14];
  const int u = blockIdx.x;
  const int tid = threadIdx.x;

  if (u >= 3584) {
    // ---- Wt prepack (2400 units) ----
    const int t_ = u - 3584;
    const int c = t_ % 96;
    const int by = t_ / 96;  // 0..24
    if (by == 0 && tid == 0) {
      float s = 0.f;
      if (c < NCLSv)
        for (int b = 0; b < NBIN; ++b) s += b_score[c * NBIN + b];
      else if (c < NOUT)
        for (int b = 0; b < NBIN; ++b) s += b_bbox[(c - NCLSv) * NBIN + b];
      bias_mean[c] = s * (1.0f / NBIN);
    }
    const int k0 = by * 1024 + tid * 4;
    if (k0 >= KTOT) return;
    const int bin = k0 >> 9, f = k0 & 511;
    float4 v = make_float4(0.f, 0.f, 0.f, 0.f);
    if (c < NCLSv)
      v = *(const float4*)(w_score + ((size_t)(c * NBIN + bin)) * FPv + f);
    else if (c < NOUT)
      v = *(const float4*)(w_bbox + ((size_t)((c - NCLSv) * NBIN + bin)) * FPv + f);
    ushort4 o;
    o.x = f2bf(v.x); o.y = f2bf(v.y); o.z = f2bf(v.z); o.w = f2bf(v.w);
    *(ushort4*)(Wt + ((size_t)bin * 96 + c) * FPv + f) = o;
    return;
  }

  // ---- pooling (3584 units) ----
  const int r = u & 511;
  const int ph = u >> 9;  // 0..6
  const float* ro = rois + (size_t)r * 5;

  float stride_f;
  {
    const int iv = ((const int*)stride_ptr)[0];
    if (iv >= 1 && iv <= 4096) stride_f = (float)iv;
    else stride_f = ((const float*)stride_ptr)[0];
  }
  const float inv = 1.0f / stride_f;

  if (tid < 2) {
    const float y1v = ro[2] * inv, y2v = ro[4] * inv;
    const float bhf = fmaxf(y2v - y1v, 0.1f) * (1.0f / 7.0f);
    const int sy = tid;
    float yy = y1v + ((float)ph + ((float)sy + 0.5f) * 0.5f) * bhf;
    yy = fminf(fmaxf(yy, 0.f), (float)(Hf - 1));
    const float y0f = floorf(yy);
    ys0[tid] = (int)y0f;
    ys1[tid] = min((int)y0f + 1, Hf - 1);
    wys[tid] = yy - y0f;
  } else if (tid >= 64 && tid < 78) {
    const int s = tid - 64;
    const float x1v = ro[1] * inv, x2v = ro[3] * inv;
    const float bwf = fmaxf(x2v - x1v, 0.1f) * (1.0f / 7.0f);
    const int pw = s >> 1, sx = s & 1;
    float xx = x1v + ((float)pw + ((float)sx + 0.5f) * 0.5f) * bwf;
    xx = fminf(fmaxf(xx, 0.f), (float)(Wfv - 1));
    const float x0f = floorf(xx);
    xs0[s] = (int)x0f;
    xs1[s] = min((int)x0f + 1, Wfv - 1);
    wxs[s] = xx - x0f;
  }
  __syncthreads();

  const int b = (int)ro[0];
  const unsigned short* xb = x_bf + (size_t)b * HWC * FPv;
  const int f2 = tid * 2;

  float acc[7][2] = {};
#pragma unroll
  for (int sy = 0; sy < 2; ++sy) {
    const int ry0 = ys0[sy] * Wfv;
    const int ry1 = ys1[sy] * Wfv;
    const float wy = wys[sy];
    const float cy = 1.f - wy;
#pragma unroll
    for (int pwsx = 0; pwsx < 14; ++pwsx) {
      const int xi0 = xs0[pwsx], xi1 = xs1[pwsx];
      const float wx = wxs[pwsx];
      const float cx = 1.f - wx;
      const unsigned u00 = *(const unsigned*)(xb + (size_t)(ry0 + xi0) * FPv + f2);
      const unsigned u01 = *(const unsigned*)(xb + (size_t)(ry0 + xi1) * FPv + f2);
      const unsigned u10 = *(const unsigned*)(xb + (size_t)(ry1 + xi0) * FPv + f2);
      const unsigned u11 = *(const unsigned*)(xb + (size_t)(ry1 + xi1) * FPv + f2);
      const float w00 = cy * cx, w01 = cy * wx, w10 = wy * cx, w11 = wy * wx;
      const int pw = pwsx >> 1;
      acc[pw][0] += w00 * bflo(u00) + w01 * bflo(u01) + w10 * bflo(u10) + w11 * bflo(u11);
      acc[pw][1] += w00 * bfhi(u00) + w01 * bfhi(u01) + w10 * bfhi(u10) + w11 * bfhi(u11);
    }
  }
  // bin-major: P[bin][r][f], bin = ph*7+pw
#pragma unroll
  for (int pw = 0; pw < 7; ++pw) {
    const unsigned lo = f2bf(acc[pw][0] * 0.25f);
    const unsigned hi = f2bf(acc[pw][1] * 0.25f);
    P_u[((size_t)(ph * 7 + pw) * RNUM + r) * (FPv / 2) + tid] = lo | (hi << 16);
  }
}

// ---------------------------------------------------------------------------
// Kernel 3: MFMA GEMM, split-K by bin (R14 verbatim, bin-major operands).
// ---------------------------------------------------------------------------
__global__ __launch_bounds__(256) void gemm2_kernel(
    const unsigned short* __restrict__ P, const unsigned short* __restrict__ Wt,
    float* __restrict__ partial) {
  __shared__ unsigned short Bs[96 * B2STRIDE];
  const int tid = threadIdx.x;
  const int lane = tid & 63, wid = tid >> 6;
  const int rt = blockIdx.x;   // 0..7
  const int bin = blockIdx.y;  // 0..48
  const int arow = rt * 64 + wid * 16 + (lane & 15);
  const int fr_f = lane & 15;
  const int fr_k = (lane >> 4) << 3;
  const unsigned short* Ap = P + ((size_t)bin * RNUM + arow) * FPv + fr_k;
  int srow[3], scol[3];
#pragma unroll
  for (int g = 0; g < 3; ++g) {
    const int idx = tid * 48 + g * 16;
    srow[g] = idx >> 7;
    scol[g] = idx & 127;
  }
  const unsigned short* WtB = Wt + (size_t)bin * 96 * FPv;

  uint4 breg[6];
  bf16x8 aCur[4], aNxt[4];
#pragma unroll
  for (int g = 0; g < 3; ++g) {
    const unsigned short* src = WtB + (size_t)srow[g] * FPv + scol[g];
    breg[g * 2] = *(const uint4*)src;
    breg[g * 2 + 1] = *(const uint4*)(src + 8);
  }
#pragma unroll
  for (int s = 0; s < 4; ++s) aCur[s] = *(const bf16x8*)(Ap + s * 32);

  f32x4 acc[6] = {};
  for (int kc = 0; kc < FPv; kc += 128) {
    __syncthreads();
#pragma unroll
    for (int g = 0; g < 3; ++g) {
      unsigned short* dst = &Bs[srow[g] * B2STRIDE + scol[g]];
      *(uint4*)dst = breg[g * 2];
      *(uint4*)(dst + 8) = breg[g * 2 + 1];
    }
    const int kn = kc + 128;
    if (kn < FPv) {
#pragma unroll
      for (int g = 0; g < 3; ++g) {
        const unsigned short* src = WtB + (size_t)srow[g] * FPv + kn + scol[g];
        breg[g * 2] = *(const uint4*)src;
        breg[g * 2 + 1] = *(const uint4*)(src + 8);
      }
#pragma unroll
      for (int s = 0; s < 4; ++s) aNxt[s] = *(const bf16x8*)(Ap + kn + s * 32);
    }
    __syncthreads();
#pragma unroll
    for (int s = 0; s < 4; ++s) {
#pragma unroll
      for (int n = 0; n < 6; ++n) {
        const bf16x8 bv =
            *(const bf16x8*)&Bs[(fr_f + n * 16) * B2STRIDE + s * 32 + fr_k];
        acc[n] =
            __builtin_amdgcn_mfma_f32_16x16x32_bf16(aCur[s], bv, acc[n], 0, 0, 0);
      }
    }
#pragma unroll
    for (int s = 0; s < 4; ++s) aCur[s] = aNxt[s];
  }
  const int c_lo = lane & 15;
  const int rr = rt * 64 + wid * 16 + ((lane >> 4) << 2);
  float* pb = partial + (size_t)bin * PARTN;
#pragma unroll
  for (int n = 0; n < 6; ++n) {
    const int c = n * 16 + c_lo;
    if (c < NOUT) {
#pragma unroll
      for (int reg = 0; reg < 4; ++reg)
        pb[(size_t)(rr + reg) * NOUT + c] = acc[n][reg];
    }
  }
}

// ---------------------------------------------------------------------------
// Kernel 4: fixed-order reduction over 49 bins + bias -> final layout.
// ---------------------------------------------------------------------------
__global__ __launch_bounds__(256) void reduce_kernel(
    const float* __restrict__ partial, const float* __restrict__ bias_mean,
    float* __restrict__ out) {
  const int g = blockIdx.x * 256 + threadIdx.x;  // 0..43519
  const int r = g / NOUT;
  const int cc = g - r * NOUT;
  float s = 0.f;
  for (int b = 0; b < NBIN; ++b) s += partial[(size_t)b * PARTN + g];
  s = s * (1.0f / NBIN) + bias_mean[cc];
  if (cc < NCLSv)
    out[(size_t)r * NCLSv + cc] = s;
  else
    out[(size_t)RNUM * NCLSv + (size_t)r * 4 + (cc - NCLSv)] = s;
}

// ---------------------------------------------------------------------------
extern "C" void kernel_launch(void* const* d_in, const int* in_sizes, int n_in,
                              void* d_out, int out_size, void* d_ws,
                              size_t ws_size, hipStream_t stream) {
  const float* rois    = (const float*)d_in[0];
  const float* feat    = (const float*)d_in[1];
  const float* w_new   = (const float*)d_in[2];
  const float* w_score = (const float*)d_in[3];
  const float* b_score = (const float*)d_in[4];
  const float* w_bbox  = (const float*)d_in[5];
  const float* b_bbox  = (const float*)d_in[6];
  const void*  stridep = d_in[7];
  float* out = (float*)d_out;

  // ws layout (256B-aligned). featT (dead after gemm1) aliases partial.
  char* w = (char*)d_ws;
  unsigned short* x_bf = (unsigned short*)w;               // 4,358,144 B
  w += ((size_t)2 * HWC * FPv * 2 + 255) & ~(size_t)255;
  unsigned short* P = (unsigned short*)w;                  // 25,690,112 B
  w += ((size_t)RNUM * KTOT * 2 + 255) & ~(size_t)255;
  unsigned short* Wt = (unsigned short*)w;                 // 4,816,896 B
  w += ((size_t)96 * KTOT * 2 + 255) & ~(size_t)255;
  char* shared_blk = w;                                    // max(featT, partial)
  unsigned short* featT = (unsigned short*)shared_blk;     // 8,716,288 B
  float* partial = (float*)shared_blk;                     // 8,529,920 B
  w += ((size_t)2 * HWC * CINv * 2 + 255) & ~(size_t)255;
  unsigned short* wn_bf = (unsigned short*)w;              // 1,048,576 B
  w += ((size_t)FPv * CINv * 2 + 255) & ~(size_t)255;
  float* bias_mean = (float*)w;                            // 384 B

  {
    prep_kernel<<<4800, 256, 0, stream>>>(w_new, feat, wn_bf, featT);
  }
  {
    // 1064 blocks = 266 hwg x 4 fb = 8 XCD x 133
    gemm1_mfma_kernel<<<1064, 256, 0, stream>>>(featT, wn_bf, x_bf);
  }
  {
    // 3584 pool units + 2400 Wt-prepack units (prepack overlaps pool)
    pool_prep_kernel<<<5984, 256, 0, stream>>>(x_bf, rois, stridep,
                                               (unsigned int*)P, w_score,
                                               b_score, w_bbox, b_bbox, Wt,
                                               bias_mean);
  }
  {
    dim3 grid(RNUM / 64, NBIN);
    gemm2_kernel<<<grid, 256, 0, stream>>>(P, Wt, partial);
  }
  {
    reduce_kernel<<<(RNUM * NOUT) / 256, 256, 0, stream>>>(partial, bias_mean,
                                                           out);
  }
}

// Round 17
// 97.053 us; speedup vs baseline: 6.2598x; 1.1881x over previous
//
#include <hip/hip_runtime.h>
#include <hip/hip_bf16.h>

#define HWC   2128      // H*W = 38*56
#define Hf    38
#define Wfv   56
#define CINv  1024
#define FPv   512       // FEAT_PLANES
#define RNUM  512
#define NCLSv 81
#define NOUT  85        // 81 cls + 4 loc
#define NBIN  49
#define KTOT  (NBIN * FPv)            // 25088
#define PARTN ((size_t)RNUM * NOUT)   // 43520

typedef short bf16x8 __attribute__((ext_vector_type(8)));
typedef float f32x4 __attribute__((ext_vector_type(4)));

static __device__ __forceinline__ unsigned short f2bf(float f) {
  __hip_bfloat16 h = __float2bfloat16(f);
  return *reinterpret_cast<unsigned short*>(&h);
}
static __device__ __forceinline__ float bflo(unsigned u) {
  return __uint_as_float((u & 0xffffu) << 16);
}
static __device__ __forceinline__ float bfhi(unsigned u) {
  return __uint_as_float(u & 0xffff0000u);
}

#define BSTRIDE1 136
#define B2STRIDE 136

// ---------------------------------------------------------------------------
// Kernel 0 (prep-lite): 4800 blocks.
//   [0,512):    w_new fp32 -> bf16
//   [512,4800): feat -> featT transpose/convert (XCD-swizzled write order)
// ---------------------------------------------------------------------------
__global__ __launch_bounds__(256) void prep_kernel(
    const float* __restrict__ w_new, const float* __restrict__ feat,
    unsigned short* __restrict__ wn_bf, unsigned short* __restrict__ featT) {
  __shared__ float t[32][33];
  const int bid = blockIdx.x;
  const int tid = threadIdx.x;
  if (bid < 512) {
    const int i = (bid * 256 + tid) * 4;  // < 512*1024
    const float4 v = *(const float4*)(w_new + i);
    ushort4 o;
    o.x = f2bf(v.x); o.y = f2bf(v.y); o.z = f2bf(v.z); o.w = f2bf(v.w);
    *(ushort4*)(wn_bf + i) = o;
    return;
  }
  const int t_ = bid - 512;                     // 0..4287
  const int wgid = (t_ & 7) * 536 + (t_ >> 3);  // bijective, 4288 = 8*536
  const int h32 = wgid >> 6;                    // 0..66
  const int rem = wgid & 63;
  const int c32 = rem >> 1;                     // 0..31
  const int bz = rem & 1;
  const int hw0 = h32 * 32;
  const int c0 = c32 * 32;
  const int tx = tid & 31, ty = tid >> 5;  // 32 x 8
  const float* fb = feat + (size_t)bz * CINv * HWC;
  const int hw = hw0 + tx;
#pragma unroll
  for (int i = 0; i < 4; ++i) {
    const int c = c0 + ty * 4 + i;
    t[ty * 4 + i][tx] = (hw < HWC) ? fb[(size_t)c * HWC + hw] : 0.f;
  }
  __syncthreads();
  unsigned short* ft = featT + (size_t)bz * HWC * CINv;
#pragma unroll
  for (int i = 0; i < 4; ++i) {
    const int hwo = hw0 + ty * 4 + i;
    if (hwo < HWC) ft[(size_t)hwo * CINv + c0 + tx] = f2bf(t[tx][ty * 4 + i]);
  }
}

// ---------------------------------------------------------------------------
// Kernel 1: MFMA GEMM v3+XCD-align (best measured variant, R14).
// 1D grid 1088 = 8 XCD x 136; swizzle (vb&7)*136+(vb>>3), hw slowest.
// Block = 4 waves of 16hw x 32f; BK=128; B in LDS (reg dbuf); A prefetched.
// ---------------------------------------------------------------------------
__global__ __launch_bounds__(256) void gemm1_mfma_kernel(
    const unsigned short* __restrict__ featT,
    const unsigned short* __restrict__ wn_bf,
    unsigned short* __restrict__ x_bf) {
  __shared__ unsigned short Bs[32 * BSTRIDE1];  // 8.7 KB
  const int tid = threadIdx.x;
  const int lane = tid & 63, wid = tid >> 6;
  const int vb = blockIdx.x;                    // 1088 = 8*136
  const int wgid = (vb & 7) * 136 + (vb >> 3);  // bijective
  const int hwg = wgid >> 5;                    // 0..33 (hw slowest)
  const int rem = wgid & 31;
  const int fg = rem >> 1;                      // 0..15
  const int b = rem & 1;
  const int f0 = fg * 32;
  const int hwbase = hwg * 64 + wid * 16;
  const int arow = min(hwbase + (lane & 15), HWC - 1);
  const int fr_f = lane & 15;
  const int fr_k = (lane >> 4) << 3;
  const unsigned short* Ap = featT + ((size_t)b * HWC + arow) * CINv + fr_k;
  const int sr = tid >> 3;
  const int sc = (tid & 7) * 16;
  const unsigned short* Bg = wn_bf + (size_t)(f0 + sr) * CINv + sc;

  uint4 breg[2];
  bf16x8 aCur[4], aNxt[4];
  breg[0] = *(const uint4*)(Bg);
  breg[1] = *(const uint4*)(Bg + 8);
#pragma unroll
  for (int s = 0; s < 4; ++s) aCur[s] = *(const bf16x8*)(Ap + s * 32);

  f32x4 acc[2] = {};
  for (int kc = 0; kc < CINv; kc += 128) {
    __syncthreads();
    *(uint4*)&Bs[sr * BSTRIDE1 + sc] = breg[0];
    *(uint4*)&Bs[sr * BSTRIDE1 + sc + 8] = breg[1];
    const int kn = kc + 128;
    if (kn < CINv) {
      breg[0] = *(const uint4*)(Bg + kn);
      breg[1] = *(const uint4*)(Bg + kn + 8);
#pragma unroll
      for (int s = 0; s < 4; ++s) aNxt[s] = *(const bf16x8*)(Ap + kn + s * 32);
    }
    __syncthreads();
#pragma unroll
    for (int s = 0; s < 4; ++s) {
#pragma unroll
      for (int n = 0; n < 2; ++n) {
        const bf16x8 bv =
            *(const bf16x8*)&Bs[(fr_f + n * 16) * BSTRIDE1 + s * 32 + fr_k];
        acc[n] =
            __builtin_amdgcn_mfma_f32_16x16x32_bf16(aCur[s], bv, acc[n], 0, 0, 0);
      }
    }
#pragma unroll
    for (int s = 0; s < 4; ++s) aCur[s] = aNxt[s];
  }
  const int c_lo = lane & 15;
  const int rbase = hwbase + ((lane >> 4) << 2);
#pragma unroll
  for (int n = 0; n < 2; ++n) {
#pragma unroll
    for (int reg = 0; reg < 4; ++reg) {
      const int hwo = rbase + reg;
      if (hwo < HWC)
        x_bf[((size_t)b * HWC + hwo) * FPv + f0 + n * 16 + c_lo] =
            f2bf(acc[n][reg]);
    }
  }
}

// ---------------------------------------------------------------------------
// Kernel 2 (pool + Wt-prepack, block-range split):
//   [0,3584):    PSRoI pooling -> P[bin][r][f] (bin-major)
//   [3584,5984): Wt[bin][96][512] prepack + bias_mean[96]
// ---------------------------------------------------------------------------
__global__ __launch_bounds__(256) void pool_prep_kernel(
    const unsigned short* __restrict__ x_bf, const float* __restrict__ rois,
    const void* __restrict__ stride_ptr, unsigned int* __restrict__ P_u,
    const float* __restrict__ w_score, const float* __restrict__ b_score,
    const float* __restrict__ w_bbox, const float* __restrict__ b_bbox,
    unsigned short* __restrict__ Wt, float* __restrict__ bias_mean) {
  __shared__ int ys0[2], ys1[2];
  __shared__ float wys[2];
  __shared__ int xs0[14], xs1[14];
  __shared__ float wxs[14];
  const int u = blockIdx.x;
  const int tid = threadIdx.x;

  if (u >= 3584) {
    const int t_ = u - 3584;
    const int c = t_ % 96;
    const int by = t_ / 96;  // 0..24
    if (by == 0 && tid == 0) {
      float s = 0.f;
      if (c < NCLSv)
        for (int b = 0; b < NBIN; ++b) s += b_score[c * NBIN + b];
      else if (c < NOUT)
        for (int b = 0; b < NBIN; ++b) s += b_bbox[(c - NCLSv) * NBIN + b];
      bias_mean[c] = s * (1.0f / NBIN);
    }
    const int k0 = by * 1024 + tid * 4;
    if (k0 >= KTOT) return;
    const int bin = k0 >> 9, f = k0 & 511;
    float4 v = make_float4(0.f, 0.f, 0.f, 0.f);
    if (c < NCLSv)
      v = *(const float4*)(w_score + ((size_t)(c * NBIN + bin)) * FPv + f);
    else if (c < NOUT)
      v = *(const float4*)(w_bbox + ((size_t)((c - NCLSv) * NBIN + bin)) * FPv + f);
    ushort4 o;
    o.x = f2bf(v.x); o.y = f2bf(v.y); o.z = f2bf(v.z); o.w = f2bf(v.w);
    *(ushort4*)(Wt + ((size_t)bin * 96 + c) * FPv + f) = o;
    return;
  }

  const int r = u & 511;
  const int ph = u >> 9;  // 0..6
  const float* ro = rois + (size_t)r * 5;

  float stride_f;
  {
    const int iv = ((const int*)stride_ptr)[0];
    if (iv >= 1 && iv <= 4096) stride_f = (float)iv;
    else stride_f = ((const float*)stride_ptr)[0];
  }
  const float inv = 1.0f / stride_f;

  if (tid < 2) {
    const float y1v = ro[2] * inv, y2v = ro[4] * inv;
    const float bhf = fmaxf(y2v - y1v, 0.1f) * (1.0f / 7.0f);
    const int sy = tid;
    float yy = y1v + ((float)ph + ((float)sy + 0.5f) * 0.5f) * bhf;
    yy = fminf(fmaxf(yy, 0.f), (float)(Hf - 1));
    const float y0f = floorf(yy);
    ys0[tid] = (int)y0f;
    ys1[tid] = min((int)y0f + 1, Hf - 1);
    wys[tid] = yy - y0f;
  } else if (tid >= 64 && tid < 78) {
    const int s = tid - 64;
    const float x1v = ro[1] * inv, x2v = ro[3] * inv;
    const float bwf = fmaxf(x2v - x1v, 0.1f) * (1.0f / 7.0f);
    const int pw = s >> 1, sx = s & 1;
    float xx = x1v + ((float)pw + ((float)sx + 0.5f) * 0.5f) * bwf;
    xx = fminf(fmaxf(xx, 0.f), (float)(Wfv - 1));
    const float x0f = floorf(xx);
    xs0[s] = (int)x0f;
    xs1[s] = min((int)x0f + 1, Wfv - 1);
    wxs[s] = xx - x0f;
  }
  __syncthreads();

  const int b = (int)ro[0];
  const unsigned short* xb = x_bf + (size_t)b * HWC * FPv;
  const int f2 = tid * 2;

  float acc[7][2] = {};
#pragma unroll
  for (int sy = 0; sy < 2; ++sy) {
    const int ry0 = ys0[sy] * Wfv;
    const int ry1 = ys1[sy] * Wfv;
    const float wy = wys[sy];
    const float cy = 1.f - wy;
#pragma unroll
    for (int pwsx = 0; pwsx < 14; ++pwsx) {
      const int xi0 = xs0[pwsx], xi1 = xs1[pwsx];
      const float wx = wxs[pwsx];
      const float cx = 1.f - wx;
      const unsigned u00 = *(const unsigned*)(xb + (size_t)(ry0 + xi0) * FPv + f2);
      const unsigned u01 = *(const unsigned*)(xb + (size_t)(ry0 + xi1) * FPv + f2);
      const unsigned u10 = *(const unsigned*)(xb + (size_t)(ry1 + xi0) * FPv + f2);
      const unsigned u11 = *(const unsigned*)(xb + (size_t)(ry1 + xi1) * FPv + f2);
      const float w00 = cy * cx, w01 = cy * wx, w10 = wy * cx, w11 = wy * wx;
      const int pw = pwsx >> 1;
      acc[pw][0] += w00 * bflo(u00) + w01 * bflo(u01) + w10 * bflo(u10) + w11 * bflo(u11);
      acc[pw][1] += w00 * bfhi(u00) + w01 * bfhi(u01) + w10 * bfhi(u10) + w11 * bfhi(u11);
    }
  }
#pragma unroll
  for (int pw = 0; pw < 7; ++pw) {
    const unsigned lo = f2bf(acc[pw][0] * 0.25f);
    const unsigned hi = f2bf(acc[pw][1] * 0.25f);
    P_u[((size_t)(ph * 7 + pw) * RNUM + r) * (FPv / 2) + tid] = lo | (hi << 16);
  }
}

// ---------------------------------------------------------------------------
// Kernel 3: MFMA GEMM, split-K by bin (bin-major operands, R14 verbatim).
// ---------------------------------------------------------------------------
__global__ __launch_bounds__(256) void gemm2_kernel(
    const unsigned short* __restrict__ P, const unsigned short* __restrict__ Wt,
    float* __restrict__ partial) {
  __shared__ unsigned short Bs[96 * B2STRIDE];
  const int tid = threadIdx.x;
  const int lane = tid & 63, wid = tid >> 6;
  const int rt = blockIdx.x;   // 0..7
  const int bin = blockIdx.y;  // 0..48
  const int arow = rt * 64 + wid * 16 + (lane & 15);
  const int fr_f = lane & 15;
  const int fr_k = (lane >> 4) << 3;
  const unsigned short* Ap = P + ((size_t)bin * RNUM + arow) * FPv + fr_k;
  int srow[3], scol[3];
#pragma unroll
  for (int g = 0; g < 3; ++g) {
    const int idx = tid * 48 + g * 16;
    srow[g] = idx >> 7;
    scol[g] = idx & 127;
  }
  const unsigned short* WtB = Wt + (size_t)bin * 96 * FPv;

  uint4 breg[6];
  bf16x8 aCur[4], aNxt[4];
#pragma unroll
  for (int g = 0; g < 3; ++g) {
    const unsigned short* src = WtB + (size_t)srow[g] * FPv + scol[g];
    breg[g * 2] = *(const uint4*)src;
    breg[g * 2 + 1] = *(const uint4*)(src + 8);
  }
#pragma unroll
  for (int s = 0; s < 4; ++s) aCur[s] = *(const bf16x8*)(Ap + s * 32);

  f32x4 acc[6] = {};
  for (int kc = 0; kc < FPv; kc += 128) {
    __syncthreads();
#pragma unroll
    for (int g = 0; g < 3; ++g) {
      unsigned short* dst = &Bs[srow[g] * B2STRIDE + scol[g]];
      *(uint4*)dst = breg[g * 2];
      *(uint4*)(dst + 8) = breg[g * 2 + 1];
    }
    const int kn = kc + 128;
    if (kn < FPv) {
#pragma unroll
      for (int g = 0; g < 3; ++g) {
        const unsigned short* src = WtB + (size_t)srow[g] * FPv + kn + scol[g];
        breg[g * 2] = *(const uint4*)src;
        breg[g * 2 + 1] = *(const uint4*)(src + 8);
      }
#pragma unroll
      for (int s = 0; s < 4; ++s) aNxt[s] = *(const bf16x8*)(Ap + kn + s * 32);
    }
    __syncthreads();
#pragma unroll
    for (int s = 0; s < 4; ++s) {
#pragma unroll
      for (int n = 0; n < 6; ++n) {
        const bf16x8 bv =
            *(const bf16x8*)&Bs[(fr_f + n * 16) * B2STRIDE + s * 32 + fr_k];
        acc[n] =
            __builtin_amdgcn_mfma_f32_16x16x32_bf16(aCur[s], bv, acc[n], 0, 0, 0);
      }
    }
#pragma unroll
    for (int s = 0; s < 4; ++s) aCur[s] = aNxt[s];
  }
  const int c_lo = lane & 15;
  const int rr = rt * 64 + wid * 16 + ((lane >> 4) << 2);
  float* pb = partial + (size_t)bin * PARTN;
#pragma unroll
  for (int n = 0; n < 6; ++n) {
    const int c = n * 16 + c_lo;
    if (c < NOUT) {
#pragma unroll
      for (int reg = 0; reg < 4; ++reg)
        pb[(size_t)(rr + reg) * NOUT + c] = acc[n][reg];
    }
  }
}

// ---------------------------------------------------------------------------
// Kernel 4: fixed-order reduction over 49 bins + bias -> final layout.
// ---------------------------------------------------------------------------
__global__ __launch_bounds__(256) void reduce_kernel(
    const float* __restrict__ partial, const float* __restrict__ bias_mean,
    float* __restrict__ out) {
  const int g = blockIdx.x * 256 + threadIdx.x;  // 0..43519
  const int r = g / NOUT;
  const int cc = g - r * NOUT;
  float s = 0.f;
  for (int b = 0; b < NBIN; ++b) s += partial[(size_t)b * PARTN + g];
  s = s * (1.0f / NBIN) + bias_mean[cc];
  if (cc < NCLSv)
    out[(size_t)r * NCLSv + cc] = s;
  else
    out[(size_t)RNUM * NCLSv + (size_t)r * 4 + (cc - NCLSv)] = s;
}

// ---------------------------------------------------------------------------
extern "C" void kernel_launch(void* const* d_in, const int* in_sizes, int n_in,
                              void* d_out, int out_size, void* d_ws,
                              size_t ws_size, hipStream_t stream) {
  const float* rois    = (const float*)d_in[0];
  const float* feat    = (const float*)d_in[1];
  const float* w_new   = (const float*)d_in[2];
  const float* w_score = (const float*)d_in[3];
  const float* b_score = (const float*)d_in[4];
  const float* w_bbox  = (const float*)d_in[5];
  const float* b_bbox  = (const float*)d_in[6];
  const void*  stridep = d_in[7];
  float* out = (float*)d_out;

  // ws layout (256B-aligned). featT (dead after gemm1) aliases partial.
  char* w = (char*)d_ws;
  unsigned short* x_bf = (unsigned short*)w;               // 4,358,144 B
  w += ((size_t)2 * HWC * FPv * 2 + 255) & ~(size_t)255;
  unsigned short* P = (unsigned short*)w;                  // 25,690,112 B
  w += ((size_t)RNUM * KTOT * 2 + 255) & ~(size_t)255;
  unsigned short* Wt = (unsigned short*)w;                 // 4,816,896 B
  w += ((size_t)96 * KTOT * 2 + 255) & ~(size_t)255;
  char* shared_blk = w;                                    // max(featT, partial)
  unsigned short* featT = (unsigned short*)shared_blk;     // 8,716,288 B
  float* partial = (float*)shared_blk;                     // 8,529,920 B
  w += ((size_t)2 * HWC * CINv * 2 + 255) & ~(size_t)255;
  unsigned short* wn_bf = (unsigned short*)w;              // 1,048,576 B
  w += ((size_t)FPv * CINv * 2 + 255) & ~(size_t)255;
  float* bias_mean = (float*)w;                            // 384 B

  {
    prep_kernel<<<4800, 256, 0, stream>>>(w_new, feat, wn_bf, featT);
  }
  {
    // 1088 = 8 XCD x 136 (v3-XCD, best measured gemm1)
    gemm1_mfma_kernel<<<1088, 256, 0, stream>>>(featT, wn_bf, x_bf);
  }
  {
    // 3584 pool units + 2400 Wt-prepack units (prepack overlaps pool)
    pool_prep_kernel<<<5984, 256, 0, stream>>>(x_bf, rois, stridep,
                                               (unsigned int*)P, w_score,
                                               b_score, w_bbox, b_bbox, Wt,
                                               bias_mean);
  }
  {
    dim3 grid(RNUM / 64, NBIN);
    gemm2_kernel<<<grid, 256, 0, stream>>>(P, Wt, partial);
  }
  {
    reduce_kernel<<<(RNUM * NOUT) / 256, 256, 0, stream>>>(partial, bias_mean,
                                                           out);
  }
}

// Round 18
// 83.746 us; speedup vs baseline: 7.2545x; 1.1589x over previous
//
#include <hip/hip_runtime.h>
#include <hip/hip_bf16.h>

#define HWC   2128      // H*W = 38*56
#define Hf    38
#define Wfv   56
#define CINv  1024
#define FPv   512       // FEAT_PLANES
#define RNUM  512
#define NCLSv 81
#define NOUT  85        // 81 cls + 4 loc
#define NBIN  49
#define KTOT  (NBIN * FPv)            // 25088
#define PARTN ((size_t)RNUM * NOUT)   // 43520

typedef short bf16x8 __attribute__((ext_vector_type(8)));
typedef float f32x4 __attribute__((ext_vector_type(4)));

static __device__ __forceinline__ unsigned short f2bf(float f) {
  __hip_bfloat16 h = __float2bfloat16(f);
  return *reinterpret_cast<unsigned short*>(&h);
}
static __device__ __forceinline__ float bflo(unsigned u) {
  return __uint_as_float((u & 0xffffu) << 16);
}
static __device__ __forceinline__ float bfhi(unsigned u) {
  return __uint_as_float(u & 0xffff0000u);
}

// async global->LDS, 16B per lane; LDS dest = wave-uniform base + lane*16.
static __device__ __forceinline__ void gload16(const unsigned short* g,
                                               unsigned short* l) {
  __builtin_amdgcn_global_load_lds(
      (const __attribute__((address_space(1))) void*)g,
      (__attribute__((address_space(3))) void*)l, 16, 0, 0);
}

#define B2STRIDE 136

// ---------------------------------------------------------------------------
// Kernel 0 (prep-lite): 4800 blocks.
//   [0,512):    w_new fp32 -> bf16
//   [512,4800): feat -> featT transpose/convert (XCD-swizzled write order)
// ---------------------------------------------------------------------------
__global__ __launch_bounds__(256) void prep_kernel(
    const float* __restrict__ w_new, const float* __restrict__ feat,
    unsigned short* __restrict__ wn_bf, unsigned short* __restrict__ featT) {
  __shared__ float t[32][33];
  const int bid = blockIdx.x;
  const int tid = threadIdx.x;
  if (bid < 512) {
    const int i = (bid * 256 + tid) * 4;  // < 512*1024
    const float4 v = *(const float4*)(w_new + i);
    ushort4 o;
    o.x = f2bf(v.x); o.y = f2bf(v.y); o.z = f2bf(v.z); o.w = f2bf(v.w);
    *(ushort4*)(wn_bf + i) = o;
    return;
  }
  const int t_ = bid - 512;                     // 0..4287
  const int wgid = (t_ & 7) * 536 + (t_ >> 3);  // bijective, 4288 = 8*536
  const int h32 = wgid >> 6;                    // 0..66
  const int rem = wgid & 63;
  const int c32 = rem >> 1;                     // 0..31
  const int bz = rem & 1;
  const int hw0 = h32 * 32;
  const int c0 = c32 * 32;
  const int tx = tid & 31, ty = tid >> 5;  // 32 x 8
  const float* fb = feat + (size_t)bz * CINv * HWC;
  const int hw = hw0 + tx;
#pragma unroll
  for (int i = 0; i < 4; ++i) {
    const int c = c0 + ty * 4 + i;
    t[ty * 4 + i][tx] = (hw < HWC) ? fb[(size_t)c * HWC + hw] : 0.f;
  }
  __syncthreads();
  unsigned short* ft = featT + (size_t)bz * HWC * CINv;
#pragma unroll
  for (int i = 0; i < 4; ++i) {
    const int hwo = hw0 + ty * 4 + i;
    if (hwo < HWC) ft[(size_t)hwo * CINv + c0 + tx] = f2bf(t[tx][ty * 4 + i]);
  }
}

// ---------------------------------------------------------------------------
// Kernel 1: MFMA GEMM v7 = v3-XCD + global_load_lds B-staging.
// 1D grid 1088 = 8 XCD x 136; swizzle (vb&7)*136+(vb>>3), hw slowest.
// Block = 4 waves of 16hw x 32f; BK=128.
// B: Bs[2][32x128] linear dbuf via gload_lds (2 issues/wave/chunk), XOR
//    swizzle byte^=(row&7)<<4 applied at the GLOBAL SOURCE (m173 pattern)
//    and on fragment reads -> conflict-free without padding.
// A: register prefetch (aCur/aNxt), as in v3. ONE barrier per chunk.
// K-order identical to v3 -> bitwise-same x_bf.
// ---------------------------------------------------------------------------
__global__ __launch_bounds__(256) void gemm1_mfma_kernel(
    const unsigned short* __restrict__ featT,
    const unsigned short* __restrict__ wn_bf,
    unsigned short* __restrict__ x_bf) {
  __shared__ unsigned short Bs[2][32 * 128];    // 16 KB dbuf
  const int tid = threadIdx.x;
  const int lane = tid & 63, wid = tid >> 6;
  const int vb = blockIdx.x;                    // 1088 = 8*136
  const int wgid = (vb & 7) * 136 + (vb >> 3);  // bijective
  const int hwg = wgid >> 5;                    // 0..33 (hw slowest)
  const int rem = wgid & 31;
  const int fg = rem >> 1;                      // 0..15
  const int b = rem & 1;
  const int f0 = fg * 32;
  const int hwbase = hwg * 64 + wid * 16;
  const int arow = min(hwbase + (lane & 15), HWC - 1);
  const int fr_f = lane & 15;
  const int fr_k = (lane >> 4) << 3;
  const unsigned short* Ap = featT + ((size_t)b * HWC + arow) * CINv + fr_k;

  // gload_lds mapping: issue q = wid*2+i covers tile bytes [q*1024, +1024)
  // = rows q*4 + (lane>>4), in-row byte cb = (lane&15)*16. Pre-swizzled
  // source column (elements): (cb ^ ((row&7)<<4)) >> 1.
  int brow[2], bcol[2];
#pragma unroll
  for (int i = 0; i < 2; ++i) {
    const int q = wid * 2 + i;
    const int row = q * 4 + (lane >> 4);
    const int cb = (lane & 15) * 16;
    brow[i] = row;
    bcol[i] = (cb ^ ((row & 7) << 4)) >> 1;
  }

  // fragment read columns (elements within a 128-elem row), same XOR mask
  // (note: (fr_f+16)&7 == fr_f&7, so one mask serves both n=0,1)
  int col[4];
#pragma unroll
  for (int s = 0; s < 4; ++s) col[s] = (s * 32 + fr_k) ^ ((fr_f & 7) << 3);

  bf16x8 aCur[4], aNxt[4];
  // prologue: issue chunk 0, prefetch A chunk 0
#pragma unroll
  for (int i = 0; i < 2; ++i)
    gload16(wn_bf + (size_t)(f0 + brow[i]) * CINv + bcol[i],
            &Bs[0][(wid * 2 + i) * 512]);
#pragma unroll
  for (int s = 0; s < 4; ++s) aCur[s] = *(const bf16x8*)(Ap + s * 32);

  f32x4 acc[2] = {};
  int buf = 0;
  for (int kc = 0; kc < CINv; kc += 128) {
    __syncthreads();  // drains DMA for Bs[buf] (compiler vmcnt(0) + barrier)
    const int kn = kc + 128;
    if (kn < CINv) {
#pragma unroll
      for (int i = 0; i < 2; ++i)
        gload16(wn_bf + (size_t)(f0 + brow[i]) * CINv + kn + bcol[i],
                &Bs[buf ^ 1][(wid * 2 + i) * 512]);
#pragma unroll
      for (int s = 0; s < 4; ++s) aNxt[s] = *(const bf16x8*)(Ap + kn + s * 32);
    }
#pragma unroll
    for (int s = 0; s < 4; ++s) {
#pragma unroll
      for (int n = 0; n < 2; ++n) {
        const bf16x8 bv =
            *(const bf16x8*)&Bs[buf][(fr_f + n * 16) * 128 + col[s]];
        acc[n] =
            __builtin_amdgcn_mfma_f32_16x16x32_bf16(aCur[s], bv, acc[n], 0, 0, 0);
      }
    }
#pragma unroll
    for (int s = 0; s < 4; ++s) aCur[s] = aNxt[s];
    buf ^= 1;
  }
  // D: col = lane&15 (f), row = (lane>>4)*4 + reg (hw)
  const int c_lo = lane & 15;
  const int rbase = hwbase + ((lane >> 4) << 2);
#pragma unroll
  for (int n = 0; n < 2; ++n) {
#pragma unroll
    for (int reg = 0; reg < 4; ++reg) {
      const int hwo = rbase + reg;
      if (hwo < HWC)
        x_bf[((size_t)b * HWC + hwo) * FPv + f0 + n * 16 + c_lo] =
            f2bf(acc[n][reg]);
    }
  }
}

// ---------------------------------------------------------------------------
// Kernel 2 (pool + Wt-prepack, block-range split):
//   [0,3584):    PSRoI pooling -> P[bin][r][f] (bin-major)
//   [3584,5984): Wt[bin][96][512] prepack + bias_mean[96]
// ---------------------------------------------------------------------------
__global__ __launch_bounds__(256) void pool_prep_kernel(
    const unsigned short* __restrict__ x_bf, const float* __restrict__ rois,
    const void* __restrict__ stride_ptr, unsigned int* __restrict__ P_u,
    const float* __restrict__ w_score, const float* __restrict__ b_score,
    const float* __restrict__ w_bbox, const float* __restrict__ b_bbox,
    unsigned short* __restrict__ Wt, float* __restrict__ bias_mean) {
  __shared__ int ys0[2], ys1[2];
  __shared__ float wys[2];
  __shared__ int xs0[14], xs1[14];
  __shared__ float wxs[14];
  const int u = blockIdx.x;
  const int tid = threadIdx.x;

  if (u >= 3584) {
    const int t_ = u - 3584;
    const int c = t_ % 96;
    const int by = t_ / 96;  // 0..24
    if (by == 0 && tid == 0) {
      float s = 0.f;
      if (c < NCLSv)
        for (int b = 0; b < NBIN; ++b) s += b_score[c * NBIN + b];
      else if (c < NOUT)
        for (int b = 0; b < NBIN; ++b) s += b_bbox[(c - NCLSv) * NBIN + b];
      bias_mean[c] = s * (1.0f / NBIN);
    }
    const int k0 = by * 1024 + tid * 4;
    if (k0 >= KTOT) return;
    const int bin = k0 >> 9, f = k0 & 511;
    float4 v = make_float4(0.f, 0.f, 0.f, 0.f);
    if (c < NCLSv)
      v = *(const float4*)(w_score + ((size_t)(c * NBIN + bin)) * FPv + f);
    else if (c < NOUT)
      v = *(const float4*)(w_bbox + ((size_t)((c - NCLSv) * NBIN + bin)) * FPv + f);
    ushort4 o;
    o.x = f2bf(v.x); o.y = f2bf(v.y); o.z = f2bf(v.z); o.w = f2bf(v.w);
    *(ushort4*)(Wt + ((size_t)bin * 96 + c) * FPv + f) = o;
    return;
  }

  const int r = u & 511;
  const int ph = u >> 9;  // 0..6
  const float* ro = rois + (size_t)r * 5;

  float stride_f;
  {
    const int iv = ((const int*)stride_ptr)[0];
    if (iv >= 1 && iv <= 4096) stride_f = (float)iv;
    else stride_f = ((const float*)stride_ptr)[0];
  }
  const float inv = 1.0f / stride_f;

  if (tid < 2) {
    const float y1v = ro[2] * inv, y2v = ro[4] * inv;
    const float bhf = fmaxf(y2v - y1v, 0.1f) * (1.0f / 7.0f);
    const int sy = tid;
    float yy = y1v + ((float)ph + ((float)sy + 0.5f) * 0.5f) * bhf;
    yy = fminf(fmaxf(yy, 0.f), (float)(Hf - 1));
    const float y0f = floorf(yy);
    ys0[tid] = (int)y0f;
    ys1[tid] = min((int)y0f + 1, Hf - 1);
    wys[tid] = yy - y0f;
  } else if (tid >= 64 && tid < 78) {
    const int s = tid - 64;
    const float x1v = ro[1] * inv, x2v = ro[3] * inv;
    const float bwf = fmaxf(x2v - x1v, 0.1f) * (1.0f / 7.0f);
    const int pw = s >> 1, sx = s & 1;
    float xx = x1v + ((float)pw + ((float)sx + 0.5f) * 0.5f) * bwf;
    xx = fminf(fmaxf(xx, 0.f), (float)(Wfv - 1));
    const float x0f = floorf(xx);
    xs0[s] = (int)x0f;
    xs1[s] = min((int)x0f + 1, Wfv - 1);
    wxs[s] = xx - x0f;
  }
  __syncthreads();

  const int b = (int)ro[0];
  const unsigned short* xb = x_bf + (size_t)b * HWC * FPv;
  const int f2 = tid * 2;

  float acc[7][2] = {};
#pragma unroll
  for (int sy = 0; sy < 2; ++sy) {
    const int ry0 = ys0[sy] * Wfv;
    const int ry1 = ys1[sy] * Wfv;
    const float wy = wys[sy];
    const float cy = 1.f - wy;
#pragma unroll
    for (int pwsx = 0; pwsx < 14; ++pwsx) {
      const int xi0 = xs0[pwsx], xi1 = xs1[pwsx];
      const float wx = wxs[pwsx];
      const float cx = 1.f - wx;
      const unsigned u00 = *(const unsigned*)(xb + (size_t)(ry0 + xi0) * FPv + f2);
      const unsigned u01 = *(const unsigned*)(xb + (size_t)(ry0 + xi1) * FPv + f2);
      const unsigned u10 = *(const unsigned*)(xb + (size_t)(ry1 + xi0) * FPv + f2);
      const unsigned u11 = *(const unsigned*)(xb + (size_t)(ry1 + xi1) * FPv + f2);
      const float w00 = cy * cx, w01 = cy * wx, w10 = wy * cx, w11 = wy * wx;
      const int pw = pwsx >> 1;
      acc[pw][0] += w00 * bflo(u00) + w01 * bflo(u01) + w10 * bflo(u10) + w11 * bflo(u11);
      acc[pw][1] += w00 * bfhi(u00) + w01 * bfhi(u01) + w10 * bfhi(u10) + w11 * bfhi(u11);
    }
  }
#pragma unroll
  for (int pw = 0; pw < 7; ++pw) {
    const unsigned lo = f2bf(acc[pw][0] * 0.25f);
    const unsigned hi = f2bf(acc[pw][1] * 0.25f);
    P_u[((size_t)(ph * 7 + pw) * RNUM + r) * (FPv / 2) + tid] = lo | (hi << 16);
  }
}

// ---------------------------------------------------------------------------
// Kernel 3: MFMA GEMM, split-K by bin (bin-major operands, R17 verbatim).
// ---------------------------------------------------------------------------
__global__ __launch_bounds__(256) void gemm2_kernel(
    const unsigned short* __restrict__ P, const unsigned short* __restrict__ Wt,
    float* __restrict__ partial) {
  __shared__ unsigned short Bs[96 * B2STRIDE];
  const int tid = threadIdx.x;
  const int lane = tid & 63, wid = tid >> 6;
  const int rt = blockIdx.x;   // 0..7
  const int bin = blockIdx.y;  // 0..48
  const int arow = rt * 64 + wid * 16 + (lane & 15);
  const int fr_f = lane & 15;
  const int fr_k = (lane >> 4) << 3;
  const unsigned short* Ap = P + ((size_t)bin * RNUM + arow) * FPv + fr_k;
  int srow[3], scol[3];
#pragma unroll
  for (int g = 0; g < 3; ++g) {
    const int idx = tid * 48 + g * 16;
    srow[g] = idx >> 7;
    scol[g] = idx & 127;
  }
  const unsigned short* WtB = Wt + (size_t)bin * 96 * FPv;

  uint4 breg[6];
  bf16x8 aCur[4], aNxt[4];
#pragma unroll
  for (int g = 0; g < 3; ++g) {
    const unsigned short* src = WtB + (size_t)srow[g] * FPv + scol[g];
    breg[g * 2] = *(const uint4*)src;
    breg[g * 2 + 1] = *(const uint4*)(src + 8);
  }
#pragma unroll
  for (int s = 0; s < 4; ++s) aCur[s] = *(const bf16x8*)(Ap + s * 32);

  f32x4 acc[6] = {};
  for (int kc = 0; kc < FPv; kc += 128) {
    __syncthreads();
#pragma unroll
    for (int g = 0; g < 3; ++g) {
      unsigned short* dst = &Bs[srow[g] * B2STRIDE + scol[g]];
      *(uint4*)dst = breg[g * 2];
      *(uint4*)(dst + 8) = breg[g * 2 + 1];
    }
    const int kn = kc + 128;
    if (kn < FPv) {
#pragma unroll
      for (int g = 0; g < 3; ++g) {
        const unsigned short* src = WtB + (size_t)srow[g] * FPv + kn + scol[g];
        breg[g * 2] = *(const uint4*)src;
        breg[g * 2 + 1] = *(const uint4*)(src + 8);
      }
#pragma unroll
      for (int s = 0; s < 4; ++s) aNxt[s] = *(const bf16x8*)(Ap + kn + s * 32);
    }
    __syncthreads();
#pragma unroll
    for (int s = 0; s < 4; ++s) {
#pragma unroll
      for (int n = 0; n < 6; ++n) {
        const bf16x8 bv =
            *(const bf16x8*)&Bs[(fr_f + n * 16) * B2STRIDE + s * 32 + fr_k];
        acc[n] =
            __builtin_amdgcn_mfma_f32_16x16x32_bf16(aCur[s], bv, acc[n], 0, 0, 0);
      }
    }
#pragma unroll
    for (int s = 0; s < 4; ++s) aCur[s] = aNxt[s];
  }
  const int c_lo = lane & 15;
  const int rr = rt * 64 + wid * 16 + ((lane >> 4) << 2);
  float* pb = partial + (size_t)bin * PARTN;
#pragma unroll
  for (int n = 0; n < 6; ++n) {
    const int c = n * 16 + c_lo;
    if (c < NOUT) {
#pragma unroll
      for (int reg = 0; reg < 4; ++reg)
        pb[(size_t)(rr + reg) * NOUT + c] = acc[n][reg];
    }
  }
}

// ---------------------------------------------------------------------------
// Kernel 4: fixed-order reduction over 49 bins + bias -> final layout.
// ---------------------------------------------------------------------------
__global__ __launch_bounds__(256) void reduce_kernel(
    const float* __restrict__ partial, const float* __restrict__ bias_mean,
    float* __restrict__ out) {
  const int g = blockIdx.x * 256 + threadIdx.x;  // 0..43519
  const int r = g / NOUT;
  const int cc = g - r * NOUT;
  float s = 0.f;
  for (int b = 0; b < NBIN; ++b) s += partial[(size_t)b * PARTN + g];
  s = s * (1.0f / NBIN) + bias_mean[cc];
  if (cc < NCLSv)
    out[(size_t)r * NCLSv + cc] = s;
  else
    out[(size_t)RNUM * NCLSv + (size_t)r * 4 + (cc - NCLSv)] = s;
}

// ---------------------------------------------------------------------------
extern "C" void kernel_launch(void* const* d_in, const int* in_sizes, int n_in,
                              void* d_out, int out_size, void* d_ws,
                              size_t ws_size, hipStream_t stream) {
  const float* rois    = (const float*)d_in[0];
  const float* feat    = (const float*)d_in[1];
  const float* w_new   = (const float*)d_in[2];
  const float* w_score = (const float*)d_in[3];
  const float* b_score = (const float*)d_in[4];
  const float* w_bbox  = (const float*)d_in[5];
  const float* b_bbox  = (const float*)d_in[6];
  const void*  stridep = d_in[7];
  float* out = (float*)d_out;

  // ws layout (256B-aligned). featT (dead after gemm1) aliases partial.
  char* w = (char*)d_ws;
  unsigned short* x_bf = (unsigned short*)w;               // 4,358,144 B
  w += ((size_t)2 * HWC * FPv * 2 + 255) & ~(size_t)255;
  unsigned short* P = (unsigned short*)w;                  // 25,690,112 B
  w += ((size_t)RNUM * KTOT * 2 + 255) & ~(size_t)255;
  unsigned short* Wt = (unsigned short*)w;                 // 4,816,896 B
  w += ((size_t)96 * KTOT * 2 + 255) & ~(size_t)255;
  char* shared_blk = w;                                    // max(featT, partial)
  unsigned short* featT = (unsigned short*)shared_blk;     // 8,716,288 B
  float* partial = (float*)shared_blk;                     // 8,529,920 B
  w += ((size_t)2 * HWC * CINv * 2 + 255) & ~(size_t)255;
  unsigned short* wn_bf = (unsigned short*)w;              // 1,048,576 B
  w += ((size_t)FPv * CINv * 2 + 255) & ~(size_t)255;
  float* bias_mean = (float*)w;                            // 384 B

  {
    prep_kernel<<<4800, 256, 0, stream>>>(w_new, feat, wn_bf, featT);
  }
  {
    // 1088 = 8 XCD x 136 (v7: v3-XCD + global_load_lds B-staging)
    gemm1_mfma_kernel<<<1088, 256, 0, stream>>>(featT, wn_bf, x_bf);
  }
  {
    // 3584 pool units + 2400 Wt-prepack units (prepack overlaps pool)
    pool_prep_kernel<<<5984, 256, 0, stream>>>(x_bf, rois, stridep,
                                               (unsigned int*)P, w_score,
                                               b_score, w_bbox, b_bbox, Wt,
                                               bias_mean);
  }
  {
    dim3 grid(RNUM / 64, NBIN);
    gemm2_kernel<<<grid, 256, 0, stream>>>(P, Wt, partial);
  }
  {
    reduce_kernel<<<(RNUM * NOUT) / 256, 256, 0, stream>>>(partial, bias_mean,
                                                           out);
  }
}

// Round 19
// 74.193 us; speedup vs baseline: 8.1885x; 1.1287x over previous
//
#include <hip/hip_runtime.h>
#include <hip/hip_bf16.h>

#define HWC   2128      // H*W = 38*56
#define Hf    38
#define Wfv   56
#define CINv  1024
#define FPv   512       // FEAT_PLANES
#define RNUM  512
#define NCLSv 81
#define NOUT  85        // 81 cls + 4 loc
#define NBIN  49
#define KTOT  (NBIN * FPv)            // 25088
#define PARTN ((size_t)RNUM * NOUT)   // 43520

typedef short bf16x8 __attribute__((ext_vector_type(8)));
typedef float f32x4 __attribute__((ext_vector_type(4)));

static __device__ __forceinline__ unsigned short f2bf(float f) {
  __hip_bfloat16 h = __float2bfloat16(f);
  return *reinterpret_cast<unsigned short*>(&h);
}
static __device__ __forceinline__ float bflo(unsigned u) {
  return __uint_as_float((u & 0xffffu) << 16);
}
static __device__ __forceinline__ float bfhi(unsigned u) {
  return __uint_as_float(u & 0xffff0000u);
}

// async global->LDS, 16B per lane; LDS dest = wave-uniform base + lane*16.
static __device__ __forceinline__ void gload16(const unsigned short* g,
                                               unsigned short* l) {
  __builtin_amdgcn_global_load_lds(
      (const __attribute__((address_space(1))) void*)g,
      (__attribute__((address_space(3))) void*)l, 16, 0, 0);
}

// ---------------------------------------------------------------------------
// Kernel 0 (prep-lite): 4800 blocks.
//   [0,512):    w_new fp32 -> bf16
//   [512,4800): feat -> featT transpose/convert (XCD-swizzled write order)
// ---------------------------------------------------------------------------
__global__ __launch_bounds__(256) void prep_kernel(
    const float* __restrict__ w_new, const float* __restrict__ feat,
    unsigned short* __restrict__ wn_bf, unsigned short* __restrict__ featT) {
  __shared__ float t[32][33];
  const int bid = blockIdx.x;
  const int tid = threadIdx.x;
  if (bid < 512) {
    const int i = (bid * 256 + tid) * 4;  // < 512*1024
    const float4 v = *(const float4*)(w_new + i);
    ushort4 o;
    o.x = f2bf(v.x); o.y = f2bf(v.y); o.z = f2bf(v.z); o.w = f2bf(v.w);
    *(ushort4*)(wn_bf + i) = o;
    return;
  }
  const int t_ = bid - 512;                     // 0..4287
  const int wgid = (t_ & 7) * 536 + (t_ >> 3);  // bijective, 4288 = 8*536
  const int h32 = wgid >> 6;                    // 0..66
  const int rem = wgid & 63;
  const int c32 = rem >> 1;                     // 0..31
  const int bz = rem & 1;
  const int hw0 = h32 * 32;
  const int c0 = c32 * 32;
  const int tx = tid & 31, ty = tid >> 5;  // 32 x 8
  const float* fb = feat + (size_t)bz * CINv * HWC;
  const int hw = hw0 + tx;
#pragma unroll
  for (int i = 0; i < 4; ++i) {
    const int c = c0 + ty * 4 + i;
    t[ty * 4 + i][tx] = (hw < HWC) ? fb[(size_t)c * HWC + hw] : 0.f;
  }
  __syncthreads();
  unsigned short* ft = featT + (size_t)bz * HWC * CINv;
#pragma unroll
  for (int i = 0; i < 4; ++i) {
    const int hwo = hw0 + ty * 4 + i;
    if (hwo < HWC) ft[(size_t)hwo * CINv + c0 + tx] = f2bf(t[tx][ty * 4 + i]);
  }
}

// ---------------------------------------------------------------------------
// Kernel 1: MFMA GEMM v7 (R18, verified): v3-XCD + global_load_lds B-staging.
// ---------------------------------------------------------------------------
__global__ __launch_bounds__(256) void gemm1_mfma_kernel(
    const unsigned short* __restrict__ featT,
    const unsigned short* __restrict__ wn_bf,
    unsigned short* __restrict__ x_bf) {
  __shared__ unsigned short Bs[2][32 * 128];    // 16 KB dbuf
  const int tid = threadIdx.x;
  const int lane = tid & 63, wid = tid >> 6;
  const int vb = blockIdx.x;                    // 1088 = 8*136
  const int wgid = (vb & 7) * 136 + (vb >> 3);  // bijective
  const int hwg = wgid >> 5;                    // 0..33 (hw slowest)
  const int rem = wgid & 31;
  const int fg = rem >> 1;                      // 0..15
  const int b = rem & 1;
  const int f0 = fg * 32;
  const int hwbase = hwg * 64 + wid * 16;
  const int arow = min(hwbase + (lane & 15), HWC - 1);
  const int fr_f = lane & 15;
  const int fr_k = (lane >> 4) << 3;
  const unsigned short* Ap = featT + ((size_t)b * HWC + arow) * CINv + fr_k;

  int brow[2], bcol[2];
#pragma unroll
  for (int i = 0; i < 2; ++i) {
    const int q = wid * 2 + i;
    const int row = q * 4 + (lane >> 4);
    const int cb = (lane & 15) * 16;
    brow[i] = row;
    bcol[i] = (cb ^ ((row & 7) << 4)) >> 1;
  }
  int col[4];
#pragma unroll
  for (int s = 0; s < 4; ++s) col[s] = (s * 32 + fr_k) ^ ((fr_f & 7) << 3);

  bf16x8 aCur[4], aNxt[4];
#pragma unroll
  for (int i = 0; i < 2; ++i)
    gload16(wn_bf + (size_t)(f0 + brow[i]) * CINv + bcol[i],
            &Bs[0][(wid * 2 + i) * 512]);
#pragma unroll
  for (int s = 0; s < 4; ++s) aCur[s] = *(const bf16x8*)(Ap + s * 32);

  f32x4 acc[2] = {};
  int buf = 0;
  for (int kc = 0; kc < CINv; kc += 128) {
    __syncthreads();
    const int kn = kc + 128;
    if (kn < CINv) {
#pragma unroll
      for (int i = 0; i < 2; ++i)
        gload16(wn_bf + (size_t)(f0 + brow[i]) * CINv + kn + bcol[i],
                &Bs[buf ^ 1][(wid * 2 + i) * 512]);
#pragma unroll
      for (int s = 0; s < 4; ++s) aNxt[s] = *(const bf16x8*)(Ap + kn + s * 32);
    }
#pragma unroll
    for (int s = 0; s < 4; ++s) {
#pragma unroll
      for (int n = 0; n < 2; ++n) {
        const bf16x8 bv =
            *(const bf16x8*)&Bs[buf][(fr_f + n * 16) * 128 + col[s]];
        acc[n] =
            __builtin_amdgcn_mfma_f32_16x16x32_bf16(aCur[s], bv, acc[n], 0, 0, 0);
      }
    }
#pragma unroll
    for (int s = 0; s < 4; ++s) aCur[s] = aNxt[s];
    buf ^= 1;
  }
  const int c_lo = lane & 15;
  const int rbase = hwbase + ((lane >> 4) << 2);
#pragma unroll
  for (int n = 0; n < 2; ++n) {
#pragma unroll
    for (int reg = 0; reg < 4; ++reg) {
      const int hwo = rbase + reg;
      if (hwo < HWC)
        x_bf[((size_t)b * HWC + hwo) * FPv + f0 + n * 16 + c_lo] =
            f2bf(acc[n][reg]);
    }
  }
}

// ---------------------------------------------------------------------------
// Kernel 2 (pool + Wt-prepack, block-range split; R17 verbatim):
//   [0,3584):    PSRoI pooling -> P[bin][r][f] (bin-major)
//   [3584,5984): Wt[bin][96][512] prepack + bias_mean[96]
// ---------------------------------------------------------------------------
__global__ __launch_bounds__(256) void pool_prep_kernel(
    const unsigned short* __restrict__ x_bf, const float* __restrict__ rois,
    const void* __restrict__ stride_ptr, unsigned int* __restrict__ P_u,
    const float* __restrict__ w_score, const float* __restrict__ b_score,
    const float* __restrict__ w_bbox, const float* __restrict__ b_bbox,
    unsigned short* __restrict__ Wt, float* __restrict__ bias_mean) {
  __shared__ int ys0[2], ys1[2];
  __shared__ float wys[2];
  __shared__ int xs0[14], xs1[14];
  __shared__ float wxs[14];
  const int u = blockIdx.x;
  const int tid = threadIdx.x;

  if (u >= 3584) {
    const int t_ = u - 3584;
    const int c = t_ % 96;
    const int by = t_ / 96;  // 0..24
    if (by == 0 && tid == 0) {
      float s = 0.f;
      if (c < NCLSv)
        for (int b = 0; b < NBIN; ++b) s += b_score[c * NBIN + b];
      else if (c < NOUT)
        for (int b = 0; b < NBIN; ++b) s += b_bbox[(c - NCLSv) * NBIN + b];
      bias_mean[c] = s * (1.0f / NBIN);
    }
    const int k0 = by * 1024 + tid * 4;
    if (k0 >= KTOT) return;
    const int bin = k0 >> 9, f = k0 & 511;
    float4 v = make_float4(0.f, 0.f, 0.f, 0.f);
    if (c < NCLSv)
      v = *(const float4*)(w_score + ((size_t)(c * NBIN + bin)) * FPv + f);
    else if (c < NOUT)
      v = *(const float4*)(w_bbox + ((size_t)((c - NCLSv) * NBIN + bin)) * FPv + f);
    ushort4 o;
    o.x = f2bf(v.x); o.y = f2bf(v.y); o.z = f2bf(v.z); o.w = f2bf(v.w);
    *(ushort4*)(Wt + ((size_t)bin * 96 + c) * FPv + f) = o;
    return;
  }

  const int r = u & 511;
  const int ph = u >> 9;  // 0..6
  const float* ro = rois + (size_t)r * 5;

  float stride_f;
  {
    const int iv = ((const int*)stride_ptr)[0];
    if (iv >= 1 && iv <= 4096) stride_f = (float)iv;
    else stride_f = ((const float*)stride_ptr)[0];
  }
  const float inv = 1.0f / stride_f;

  if (tid < 2) {
    const float y1v = ro[2] * inv, y2v = ro[4] * inv;
    const float bhf = fmaxf(y2v - y1v, 0.1f) * (1.0f / 7.0f);
    const int sy = tid;
    float yy = y1v + ((float)ph + ((float)sy + 0.5f) * 0.5f) * bhf;
    yy = fminf(fmaxf(yy, 0.f), (float)(Hf - 1));
    const float y0f = floorf(yy);
    ys0[tid] = (int)y0f;
    ys1[tid] = min((int)y0f + 1, Hf - 1);
    wys[tid] = yy - y0f;
  } else if (tid >= 64 && tid < 78) {
    const int s = tid - 64;
    const float x1v = ro[1] * inv, x2v = ro[3] * inv;
    const float bwf = fmaxf(x2v - x1v, 0.1f) * (1.0f / 7.0f);
    const int pw = s >> 1, sx = s & 1;
    float xx = x1v + ((float)pw + ((float)sx + 0.5f) * 0.5f) * bwf;
    xx = fminf(fmaxf(xx, 0.f), (float)(Wfv - 1));
    const float x0f = floorf(xx);
    xs0[s] = (int)x0f;
    xs1[s] = min((int)x0f + 1, Wfv - 1);
    wxs[s] = xx - x0f;
  }
  __syncthreads();

  const int b = (int)ro[0];
  const unsigned short* xb = x_bf + (size_t)b * HWC * FPv;
  const int f2 = tid * 2;

  float acc[7][2] = {};
#pragma unroll
  for (int sy = 0; sy < 2; ++sy) {
    const int ry0 = ys0[sy] * Wfv;
    const int ry1 = ys1[sy] * Wfv;
    const float wy = wys[sy];
    const float cy = 1.f - wy;
#pragma unroll
    for (int pwsx = 0; pwsx < 14; ++pwsx) {
      const int xi0 = xs0[pwsx], xi1 = xs1[pwsx];
      const float wx = wxs[pwsx];
      const float cx = 1.f - wx;
      const unsigned u00 = *(const unsigned*)(xb + (size_t)(ry0 + xi0) * FPv + f2);
      const unsigned u01 = *(const unsigned*)(xb + (size_t)(ry0 + xi1) * FPv + f2);
      const unsigned u10 = *(const unsigned*)(xb + (size_t)(ry1 + xi0) * FPv + f2);
      const unsigned u11 = *(const unsigned*)(xb + (size_t)(ry1 + xi1) * FPv + f2);
      const float w00 = cy * cx, w01 = cy * wx, w10 = wy * cx, w11 = wy * wx;
      const int pw = pwsx >> 1;
      acc[pw][0] += w00 * bflo(u00) + w01 * bflo(u01) + w10 * bflo(u10) + w11 * bflo(u11);
      acc[pw][1] += w00 * bfhi(u00) + w01 * bfhi(u01) + w10 * bfhi(u10) + w11 * bfhi(u11);
    }
  }
#pragma unroll
  for (int pw = 0; pw < 7; ++pw) {
    const unsigned lo = f2bf(acc[pw][0] * 0.25f);
    const unsigned hi = f2bf(acc[pw][1] * 0.25f);
    P_u[((size_t)(ph * 7 + pw) * RNUM + r) * (FPv / 2) + tid] = lo | (hi << 16);
  }
}

// ---------------------------------------------------------------------------
// Kernel 3: MFMA GEMM v3 (gload_lds) — split-K by bin, bin-major operands.
// B chunk tile 96x128 staged via 6 gload_lds issues/wave into linear
// Bs[2][96*128] dbuf, pre-swizzled source XOR (byte^=(row&7)<<4), fragment
// reads use matching XOR. ONE barrier per chunk. A: reg prefetch.
// K-order identical to R17 gemm2 -> bitwise-same partial.
// ---------------------------------------------------------------------------
__global__ __launch_bounds__(256) void gemm2_kernel(
    const unsigned short* __restrict__ P, const unsigned short* __restrict__ Wt,
    float* __restrict__ partial) {
  __shared__ unsigned short Bs[2][96 * 128];    // 48 KB dbuf
  const int tid = threadIdx.x;
  const int lane = tid & 63, wid = tid >> 6;
  const int rt = blockIdx.x;   // 0..7
  const int bin = blockIdx.y;  // 0..48
  const int arow = rt * 64 + wid * 16 + (lane & 15);
  const int fr_f = lane & 15;
  const int fr_k = (lane >> 4) << 3;
  const unsigned short* Ap = P + ((size_t)bin * RNUM + arow) * FPv + fr_k;
  const unsigned short* WtB = Wt + (size_t)bin * 96 * FPv;

  // gload mapping: issue q = wid*6+i covers LDS bytes [q*1024, +1024)
  // = rows q*4 + (lane>>4) of the 96x128 tile, in-row byte (lane&15)*16,
  // with pre-swizzled source column.
  int brow[6], bcol[6];
#pragma unroll
  for (int i = 0; i < 6; ++i) {
    const int q = wid * 6 + i;
    const int row = q * 4 + (lane >> 4);
    const int cb = (lane & 15) * 16;
    brow[i] = row;
    bcol[i] = (cb ^ ((row & 7) << 4)) >> 1;
  }
  int col[4];
#pragma unroll
  for (int s = 0; s < 4; ++s) col[s] = (s * 32 + fr_k) ^ ((fr_f & 7) << 3);

  bf16x8 aCur[4], aNxt[4];
  // prologue: issue chunk 0, prefetch A chunk 0
#pragma unroll
  for (int i = 0; i < 6; ++i)
    gload16(WtB + (size_t)brow[i] * FPv + bcol[i],
            &Bs[0][(wid * 6 + i) * 512]);
#pragma unroll
  for (int s = 0; s < 4; ++s) aCur[s] = *(const bf16x8*)(Ap + s * 32);

  f32x4 acc[6] = {};
  int buf = 0;
  for (int kc = 0; kc < FPv; kc += 128) {
    __syncthreads();  // drains DMA for Bs[buf]
    const int kn = kc + 128;
    if (kn < FPv) {
#pragma unroll
      for (int i = 0; i < 6; ++i)
        gload16(WtB + (size_t)brow[i] * FPv + kn + bcol[i],
                &Bs[buf ^ 1][(wid * 6 + i) * 512]);
#pragma unroll
      for (int s = 0; s < 4; ++s) aNxt[s] = *(const bf16x8*)(Ap + kn + s * 32);
    }
#pragma unroll
    for (int s = 0; s < 4; ++s) {
#pragma unroll
      for (int n = 0; n < 6; ++n) {
        const bf16x8 bv =
            *(const bf16x8*)&Bs[buf][(fr_f + n * 16) * 128 + col[s]];
        acc[n] =
            __builtin_amdgcn_mfma_f32_16x16x32_bf16(aCur[s], bv, acc[n], 0, 0, 0);
      }
    }
#pragma unroll
    for (int s = 0; s < 4; ++s) aCur[s] = aNxt[s];
    buf ^= 1;
  }
  const int c_lo = lane & 15;
  const int rr = rt * 64 + wid * 16 + ((lane >> 4) << 2);
  float* pb = partial + (size_t)bin * PARTN;
#pragma unroll
  for (int n = 0; n < 6; ++n) {
    const int c = n * 16 + c_lo;
    if (c < NOUT) {
#pragma unroll
      for (int reg = 0; reg < 4; ++reg)
        pb[(size_t)(rr + reg) * NOUT + c] = acc[n][reg];
    }
  }
}

// ---------------------------------------------------------------------------
// Kernel 4: fixed-order reduction over 49 bins + bias -> final layout.
// ---------------------------------------------------------------------------
__global__ __launch_bounds__(256) void reduce_kernel(
    const float* __restrict__ partial, const float* __restrict__ bias_mean,
    float* __restrict__ out) {
  const int g = blockIdx.x * 256 + threadIdx.x;  // 0..43519
  const int r = g / NOUT;
  const int cc = g - r * NOUT;
  float s = 0.f;
  for (int b = 0; b < NBIN; ++b) s += partial[(size_t)b * PARTN + g];
  s = s * (1.0f / NBIN) + bias_mean[cc];
  if (cc < NCLSv)
    out[(size_t)r * NCLSv + cc] = s;
  else
    out[(size_t)RNUM * NCLSv + (size_t)r * 4 + (cc - NCLSv)] = s;
}

// ---------------------------------------------------------------------------
extern "C" void kernel_launch(void* const* d_in, const int* in_sizes, int n_in,
                              void* d_out, int out_size, void* d_ws,
                              size_t ws_size, hipStream_t stream) {
  const float* rois    = (const float*)d_in[0];
  const float* feat    = (const float*)d_in[1];
  const float* w_new   = (const float*)d_in[2];
  const float* w_score = (const float*)d_in[3];
  const float* b_score = (const float*)d_in[4];
  const float* w_bbox  = (const float*)d_in[5];
  const float* b_bbox  = (const float*)d_in[6];
  const void*  stridep = d_in[7];
  float* out = (float*)d_out;

  // ws layout (256B-aligned). featT (dead after gemm1) aliases partial.
  char* w = (char*)d_ws;
  unsigned short* x_bf = (unsigned short*)w;               // 4,358,144 B
  w += ((size_t)2 * HWC * FPv * 2 + 255) & ~(size_t)255;
  unsigned short* P = (unsigned short*)w;                  // 25,690,112 B
  w += ((size_t)RNUM * KTOT * 2 + 255) & ~(size_t)255;
  unsigned short* Wt = (unsigned short*)w;                 // 4,816,896 B
  w += ((size_t)96 * KTOT * 2 + 255) & ~(size_t)255;
  char* shared_blk = w;                                    // max(featT, partial)
  unsigned short* featT = (unsigned short*)shared_blk;     // 8,716,288 B
  float* partial = (float*)shared_blk;                     // 8,529,920 B
  w += ((size_t)2 * HWC * CINv * 2 + 255) & ~(size_t)255;
  unsigned short* wn_bf = (unsigned short*)w;              // 1,048,576 B
  w += ((size_t)FPv * CINv * 2 + 255) & ~(size_t)255;
  float* bias_mean = (float*)w;                            // 384 B

  {
    prep_kernel<<<4800, 256, 0, stream>>>(w_new, feat, wn_bf, featT);
  }
  {
    // 1088 = 8 XCD x 136 (v7, verified R18)
    gemm1_mfma_kernel<<<1088, 256, 0, stream>>>(featT, wn_bf, x_bf);
  }
  {
    // 3584 pool units + 2400 Wt-prepack units (prepack overlaps pool)
    pool_prep_kernel<<<5984, 256, 0, stream>>>(x_bf, rois, stridep,
                                               (unsigned int*)P, w_score,
                                               b_score, w_bbox, b_bbox, Wt,
                                               bias_mean);
  }
  {
    dim3 grid(RNUM / 64, NBIN);
    gemm2_kernel<<<grid, 256, 0, stream>>>(P, Wt, partial);
  }
  {
    reduce_kernel<<<(RNUM * NOUT) / 256, 256, 0, stream>>>(partial, bias_mean,
                                                           out);
  }
}